// Round 13
// baseline (290.936 us; speedup 1.0000x reference)
//
#include <hip/hip_runtime.h>
#include <cstdint>

#define D_MODEL 512
#define NUM_HEADS 8
#define D_HEAD 64
#define KNB 16
#define NBUCK 2048
#define KCAP 256
#define LN_EPS 1e-5f
#define FINF 3.4e38f

typedef __bf16 bf16x8v __attribute__((ext_vector_type(8)));
typedef float f32x4v __attribute__((ext_vector_type(4)));
typedef int i32x4 __attribute__((ext_vector_type(4)));
typedef const __attribute__((address_space(1))) unsigned int* gptr_t;
typedef __attribute__((address_space(3))) unsigned int* lptr_t;

__device__ __forceinline__ float wave_reduce_sum(float v) {
  #pragma unroll
  for (int off = 32; off > 0; off >>= 1) v += __shfl_xor(v, off, 64);
  return v;
}

// bf16 helpers (bit-level, round-to-nearest-even)
__device__ __forceinline__ unsigned short f2bf(float x) {
  unsigned int u = __float_as_uint(x);
  u = (u + 0x7fffu + ((u >> 16) & 1u)) >> 16;
  return (unsigned short)u;
}
__device__ __forceinline__ float bf2f(unsigned short h) {
  return __uint_as_float(((unsigned int)h) << 16);
}

// Morton helpers: bucketing quality only affects SPEED.
__device__ __forceinline__ unsigned spread3(unsigned x) {
  x &= 0x3FFu;
  x = (x | (x << 16)) & 0x030000FFu;
  x = (x | (x << 8))  & 0x0300F00Fu;
  x = (x | (x << 4))  & 0x030C30C3u;
  x = (x | (x << 2))  & 0x09249249u;
  return x;
}
__device__ __forceinline__ unsigned quant10(float v) {
  int q = (int)((v + 6.f) * (1023.f / 12.f));
  q = q < 0 ? 0 : (q > 1023 ? 1023 : q);
  return (unsigned)q;
}

// 64-lane bitonic sort ascending by (d, j) lexicographic (pairs distinct).
__device__ __forceinline__ void bitonic64(float& d, int& j, int lane) {
  #pragma unroll
  for (int k = 2; k <= 64; k <<= 1) {
    #pragma unroll
    for (int s = k >> 1; s > 0; s >>= 1) {
      const float od = __shfl_xor(d, s, 64);
      const int   oj = __shfl_xor(j, s, 64);
      const bool up = ((lane & k) == 0);
      const bool lower = ((lane & s) == 0);
      const bool oless = (od < d) || (od == d && oj < j);
      if ((lower == up) ? oless : !oless) { d = od; j = oj; }
    }
  }
}

// ---------------------------------------------------------------------------
// Kernel 0a: zero bucket histogram
// ---------------------------------------------------------------------------
__global__ void zero_hist_kernel(int* __restrict__ hist, int n) {
  const int t = blockIdx.x * blockDim.x + threadIdx.x;
  if (t < n) hist[t] = 0;
}

// ---------------------------------------------------------------------------
// Kernel 0b: pad pos -> float4, Morton bucket (top 11 bits), histogram.
// ---------------------------------------------------------------------------
__global__ void bucket_kernel(const float* __restrict__ pos,
                              float4* __restrict__ posf4,
                              int* __restrict__ hist,
                              int* __restrict__ bucketid, int total) {
  const int t = blockIdx.x * blockDim.x + threadIdx.x;
  if (t >= total) return;
  const float4 p = make_float4(pos[t * 3], pos[t * 3 + 1], pos[t * 3 + 2], 0.f);
  posf4[t] = p;
  const unsigned code = (spread3(quant10(p.z)) << 2) |
                        (spread3(quant10(p.y)) << 1) | spread3(quant10(p.x));
  const int bk = code >> 19;
  const int b = t >> 12;
  bucketid[t] = bk;
  atomicAdd(&hist[b * NBUCK + bk], 1);
}

// ---------------------------------------------------------------------------
// Kernel 0c: exclusive scan of 2048 buckets per batch (one block per batch).
// ---------------------------------------------------------------------------
__global__ __launch_bounds__(1024) void scan_kernel(const int* __restrict__ hist,
                                                    int* __restrict__ off) {
  __shared__ int lsum[16];
  const int b = blockIdx.x;
  const int tid = threadIdx.x;
  const int lane = tid & 63, wv = tid >> 6;
  const int h0 = hist[b * NBUCK + 2 * tid];
  const int h1 = hist[b * NBUCK + 2 * tid + 1];
  int v = h0 + h1;
  #pragma unroll
  for (int d = 1; d < 64; d <<= 1) {
    const int u = __shfl_up(v, d, 64);
    if (lane >= d) v += u;
  }
  if (lane == 63) lsum[wv] = v;
  __syncthreads();
  if (wv == 0) {
    int s = (lane < 16) ? lsum[lane] : 0;
    #pragma unroll
    for (int d = 1; d < 16; d <<= 1) {
      const int u = __shfl_up(s, d, 64);
      if (lane >= d) s += u;
    }
    if (lane < 16) lsum[lane] = s;
  }
  __syncthreads();
  const int base = (wv > 0) ? lsum[wv - 1] : 0;
  const int excl = v + base - (h0 + h1);
  off[b * NBUCK + 2 * tid] = excl;
  off[b * NBUCK + 2 * tid + 1] = excl + h0;
}

// ---------------------------------------------------------------------------
// Kernel 0d: scatter into bucket order.
// ---------------------------------------------------------------------------
__global__ void scatter_kernel(const float4* __restrict__ posf4,
                               const int* __restrict__ bucketid,
                               int* __restrict__ off,
                               int* __restrict__ perm,
                               float4* __restrict__ posf4s, int total) {
  const int t = blockIdx.x * blockDim.x + threadIdx.x;
  if (t >= total) return;
  const int b = t >> 12;
  const int i = t & 4095;
  const int slot = atomicAdd(&off[b * NBUCK + bucketid[t]], 1);
  perm[b * 4096 + slot] = i;
  posf4s[b * 4096 + slot] = posf4[t];
}

// ---------------------------------------------------------------------------
// Kernel 1: kNN — register-resident single scan + bitonic selection
// (unchanged from Round 12: measured fast, dropped out of top-5).
// ---------------------------------------------------------------------------
__global__ __launch_bounds__(64) void knn_kernel(const float4* __restrict__ posf4s,
                                                 int* __restrict__ idx_out,
                                                 int N) {
  __shared__ float ldsD[KCAP];
  __shared__ int   ldsJ[KCAP];
  const int qs = blockIdx.x;           // global sorted id
  const int base = qs & ~4095;
  const int n = qs - base;             // batch-local sorted pos
  const int lane = threadIdx.x;
  const float4* pb = posf4s + base;
  const float4 qp = pb[n];

  float darr[64];
  float lmin = FINF;
  #pragma unroll
  for (int it = 0; it < 64; ++it) {
    const int j = (it << 6) + lane;
    const float4 p = pb[j];
    const float dx = qp.x - p.x, dy = qp.y - p.y, dz = qp.z - p.z;
    float d = dx * dx + dy * dy + dz * dz;
    if (j == n) d = FINF;
    darr[it] = d;
    lmin = fminf(lmin, d);
  }

  float tau;
  {
    float dm = lmin;
    int jm = lane;
    bitonic64(dm, jm, lane);
    tau = __shfl(dm, 15, 64);
  }

  int count = 0;
  #pragma unroll
  for (int it = 0; it < 64; ++it) {
    const float d = darr[it];
    const bool pred = (d <= tau);
    const unsigned long long mask = __ballot(pred);
    if (pred) {
      const int slot = count + __popcll(mask & ((1ull << lane) - 1ull));
      if (slot < KCAP) { ldsD[slot] = d; ldsJ[slot] = (it << 6) + lane; }
    }
    count += (int)__popcll(mask);
  }

  if (count <= KCAP) {
    float d = (lane < count) ? ldsD[lane] : FINF;
    int   jj = (lane < count) ? ldsJ[lane] : 0x40000000 + lane;
    bitonic64(d, jj, lane);
    for (int start = 64; start < count; start += 48) {
      if (lane >= 16) {
        const int src = start + lane - 16;
        d  = (src < count) ? ldsD[src] : FINF;
        jj = (src < count) ? ldsJ[src] : 0x40000000 + lane;
      }
      bitonic64(d, jj, lane);
    }
    if (lane < KNB) idx_out[qs * KNB + lane] = jj;
  } else {
    float dist[KNB];
    int nidx[KNB];
    #pragma unroll
    for (int t = 0; t < KNB; ++t) { dist[t] = FINF; nidx[t] = -1; }
    #pragma unroll
    for (int it = 0; it < 64; ++it) {
      const float d = darr[it];
      unsigned long long mask = __ballot(d <= tau);
      while (mask) {
        const int src = __builtin_ctzll(mask);
        mask &= (mask - 1);
        const float dd = __shfl(d, src, 64);
        const int jj = (it << 6) + src;
        if (dd < dist[KNB - 1]) {
          float dc = dd;
          int ic = jj;
          #pragma unroll
          for (int t = 0; t < KNB; ++t) {
            const bool sw = dc < dist[t];
            const float od = dist[t];
            const int oi = nidx[t];
            dist[t] = sw ? dc : od;
            nidx[t] = sw ? ic : oi;
            dc = sw ? od : dc;
            ic = sw ? oi : ic;
          }
        }
      }
    }
    #pragma unroll
    for (int t = 0; t < KNB; ++t) {
      const int v = nidx[t] < 0 ? 0 : nidx[t];
      if (lane == t) idx_out[qs * KNB + t] = v;
    }
  }
}

// ---------------------------------------------------------------------------
// Kernel 2a: features -> A' bf16 Mx1024 [hi|lo], rows gathered into sorted
// order.
// ---------------------------------------------------------------------------
__global__ __launch_bounds__(256) void conv_feat_kernel(const float* __restrict__ src,
                                                        const int* __restrict__ perm,
                                                        unsigned short* __restrict__ dst,
                                                        int total4) {
  const int t = blockIdx.x * blockDim.x + threadIdx.x;
  if (t >= total4) return;
  const int f = t * 4;
  const int row = f >> 9;
  const int col = f & 511;
  const int orig = (row & ~4095) + perm[row];
  const float4 v = *(const float4*)(src + (size_t)orig * 512 + col);
  ushort4 h, l;
  h.x = f2bf(v.x); l.x = f2bf(v.x - bf2f(h.x));
  h.y = f2bf(v.y); l.y = f2bf(v.y - bf2f(h.y));
  h.z = f2bf(v.z); l.z = f2bf(v.z - bf2f(h.z));
  h.w = f2bf(v.w); l.w = f2bf(v.w - bf2f(h.w));
  *(ushort4*)(dst + (size_t)row * 1024 + col) = h;
  *(ushort4*)(dst + (size_t)row * 1024 + 512 + col) = l;
}

// ---------------------------------------------------------------------------
// Kernel 2b: weights (512x512 fp32, W[k][n]) -> transposed split bf16
// ---------------------------------------------------------------------------
__global__ __launch_bounds__(256) void conv_w_kernel(const float* __restrict__ Wq,
                                                     const float* __restrict__ Wk,
                                                     const float* __restrict__ Wv,
                                                     const float* __restrict__ Wo,
                                                     unsigned short* __restrict__ BhQKV,
                                                     unsigned short* __restrict__ BlQKV,
                                                     unsigned short* __restrict__ BhO,
                                                     unsigned short* __restrict__ BlO) {
  const int wsel = blockIdx.x >> 10;
  const int i = ((blockIdx.x & 1023) << 8) + threadIdx.x;
  const int n = i >> 9;
  const int k = i & 511;
  const float* src = wsel == 0 ? Wq : wsel == 1 ? Wk : wsel == 2 ? Wv : Wo;
  unsigned short* dh = wsel < 3 ? BhQKV + (size_t)(wsel * 512 + n) * 512
                                : BhO + (size_t)n * 512;
  unsigned short* dl = wsel < 3 ? BlQKV + (size_t)(wsel * 512 + n) * 512
                                : BlO + (size_t)n * 512;
  const float w = src[(size_t)k * 512 + n];
  const unsigned short h = f2bf(w);
  dh[k] = h;
  dl[k] = f2bf(w - bf2f(h));
}

// ---------------------------------------------------------------------------
// Kernel 3: split-bf16 MFMA GEMM — Round 13 rework:
// (a) XOR slot swizzle kills the 8-way LDS bank conflict (4.7M counted in
//     r12): slot (row,kcq) holds global quad kcq ^ ((row>>1)&3); reads use
//     the same xor -> 16 lanes cover all 8 bank groups twice = 2-way = free.
//     global_load_lds dest stays linear (wave-uniform base + lane*16); only
//     the per-lane GLOBAL address is permuted.
// (b) Merged loop 1: stage A_hi, A_lo, B_hi together (24 KB LDS) -> 32
//     MFMAs per barrier (a_hi*b_h + a_lo*b_h); loop 2 = A_hi x B_lo, 16.
//     Barrier pairs 48 -> 32; B_hi fetched once instead of twice.
// ---------------------------------------------------------------------------
__global__ __launch_bounds__(256) void gemm_split_kernel(
    const unsigned short* __restrict__ A,    // M x 1024  [hi|lo]
    const unsigned short* __restrict__ Bh,   // Ncols x 512
    const unsigned short* __restrict__ Bl,   // Ncols x 512
    float* __restrict__ C0, float* __restrict__ C1, float* __restrict__ C2) {
  __shared__ unsigned short AsH[4096];   // 128 rows x 32 halves (8 KB)
  __shared__ unsigned short AsL[4096];
  __shared__ unsigned short Bs[4096];

  const int tid = threadIdx.x;
  const int wid = tid >> 6;
  const int lane = tid & 63;
  const int lm = lane & 15;
  const int kq = lane >> 4;
  const int wr = wid >> 1;
  const int wc = wid & 1;
  const int bm = blockIdx.y, bn = blockIdx.x;
  const int rowA0 = bm * 128;
  const int rowB0 = bn * 128;

  f32x4v acc[4][4];
  #pragma unroll
  for (int mi = 0; mi < 4; ++mi)
    #pragma unroll
    for (int ni = 0; ni < 4; ++ni) {
      f32x4v z = {0.f, 0.f, 0.f, 0.f};
      acc[mi][ni] = z;
    }

  // stage one 128x32 tile: thread covers slots wid*128+{0,64}+lane;
  // slot s = row*4+kcq gets global quad kcq ^ ((row>>1)&3)
  auto stage = [&](unsigned short* dst, const unsigned short* gsrc,
                   int gstride, int grow0, int gk0) {
    #pragma unroll
    for (int i = 0; i < 2; ++i) {
      const int s = wid * 128 + i * 64 + lane;
      const int row = s >> 2;
      const int gq = (s & 3) ^ ((row >> 1) & 3);
      const unsigned short* ga =
          gsrc + (size_t)(grow0 + row) * gstride + gk0 + gq * 8;
      __builtin_amdgcn_global_load_lds((gptr_t)ga,
          (lptr_t)(dst + (size_t)(wid * 128 + i * 64) * 8), 16, 0, 0);
    }
  };
  // read quad kq of row from a swizzled tile
  auto rd = [&](const unsigned short* src, int row) -> i32x4 {
    const int sl = row * 4 + (kq ^ ((row >> 1) & 3));
    return *(const i32x4*)(src + (size_t)sl * 8);
  };

  // ---- loop 1: (A_hi + A_lo) x B_hi, 32 MFMA per barrier ----
  for (int k0 = 0; k0 < 512; k0 += 32) {
    stage(AsH, A, 1024, rowA0, k0);
    stage(AsL, A, 1024, rowA0, 512 + k0);
    stage(Bs, Bh, 512, rowB0, k0);
    __syncthreads();
    i32x4 ah[4], al[4], bb[4];
    #pragma unroll
    for (int mi = 0; mi < 4; ++mi) {
      ah[mi] = rd(AsH, wr * 64 + mi * 16 + lm);
      al[mi] = rd(AsL, wr * 64 + mi * 16 + lm);
    }
    #pragma unroll
    for (int ni = 0; ni < 4; ++ni) bb[ni] = rd(Bs, wc * 64 + ni * 16 + lm);
    #pragma unroll
    for (int mi = 0; mi < 4; ++mi)
      #pragma unroll
      for (int ni = 0; ni < 4; ++ni) {
        acc[mi][ni] = __builtin_amdgcn_mfma_f32_16x16x32_bf16(
            __builtin_bit_cast(bf16x8v, ah[mi]),
            __builtin_bit_cast(bf16x8v, bb[ni]), acc[mi][ni], 0, 0, 0);
        acc[mi][ni] = __builtin_amdgcn_mfma_f32_16x16x32_bf16(
            __builtin_bit_cast(bf16x8v, al[mi]),
            __builtin_bit_cast(bf16x8v, bb[ni]), acc[mi][ni], 0, 0, 0);
      }
    __syncthreads();
  }

  // ---- loop 2: A_hi x B_lo, 16 MFMA per barrier ----
  for (int k0 = 0; k0 < 512; k0 += 32) {
    stage(AsH, A, 1024, rowA0, k0);
    stage(Bs, Bl, 512, rowB0, k0);
    __syncthreads();
    i32x4 ah[4], bb[4];
    #pragma unroll
    for (int mi = 0; mi < 4; ++mi) ah[mi] = rd(AsH, wr * 64 + mi * 16 + lm);
    #pragma unroll
    for (int ni = 0; ni < 4; ++ni) bb[ni] = rd(Bs, wc * 64 + ni * 16 + lm);
    #pragma unroll
    for (int mi = 0; mi < 4; ++mi)
      #pragma unroll
      for (int ni = 0; ni < 4; ++ni)
        acc[mi][ni] = __builtin_amdgcn_mfma_f32_16x16x32_bf16(
            __builtin_bit_cast(bf16x8v, ah[mi]),
            __builtin_bit_cast(bf16x8v, bb[ni]), acc[mi][ni], 0, 0, 0);
    __syncthreads();
  }

  const int sel = bn >> 2;
  float* __restrict__ Cb = sel == 0 ? C0 : sel == 1 ? C1 : C2;
  const int r0 = bm * 128 + wr * 64;
  const int c0 = ((bn & 3) << 7) + wc * 64;
  // C/D layout: col = lane&15, row = (lane>>4)*4 + reg   [m89/m91]
  #pragma unroll
  for (int mi = 0; mi < 4; ++mi)
    #pragma unroll
    for (int ni = 0; ni < 4; ++ni) {
      float* Cp = Cb + (size_t)(r0 + mi * 16 + kq * 4) * 512 + c0 + ni * 16 + lm;
      #pragma unroll
      for (int r = 0; r < 4; ++r) Cp[(size_t)r * 512] = acc[mi][ni][r];
    }
}

// ---------------------------------------------------------------------------
// Kernel 4: local attention, sorted order, XCD-swizzled blocks (unchanged).
// ---------------------------------------------------------------------------
__global__ __launch_bounds__(256) void attn_kernel(const float* __restrict__ Q,
                                                   const float* __restrict__ Kb,
                                                   const float* __restrict__ Vb,
                                                   const int* __restrict__ idx,
                                                   const float4* __restrict__ posf4s,
                                                   const float* __restrict__ Wpos,
                                                   const float* __restrict__ bpos,
                                                   const float* __restrict__ temperature,
                                                   unsigned short* __restrict__ Aout,
                                                   int nblocks) {
  int bid = blockIdx.x;
  bid = (bid & 7) * (nblocks >> 3) + (bid >> 3);        // XCD-contiguous
  const int qs = bid * 4 + (threadIdx.x >> 6);
  const int lane = threadIdx.x & 63;
  const int s = lane & 7;
  const int base = qs & ~4095;

  const float inv_t = 1.0f / temperature[0];

  float q[8];
  *(float4*)&q[0] = *(const float4*)(Q + (size_t)qs * D_MODEL + lane * 8);
  *(float4*)&q[4] = *(const float4*)(Q + (size_t)qs * D_MODEL + lane * 8 + 4);

  float wp[3][8], bp[8];
  #pragma unroll
  for (int c = 0; c < 3; ++c) {
    *(float4*)&wp[c][0] = *(const float4*)(Wpos + c * 128 + s * 8);
    *(float4*)&wp[c][4] = *(const float4*)(Wpos + c * 128 + s * 8 + 4);
  }
  *(float4*)&bp[0] = *(const float4*)(bpos + s * 8);
  *(float4*)&bp[4] = *(const float4*)(bpos + s * 8 + 4);
  float qw0 = 0.f, qw1 = 0.f, qw2 = 0.f, qb = 0.f;
  #pragma unroll
  for (int j = 0; j < 8; ++j) {
    qw0 += q[j] * wp[0][j];
    qw1 += q[j] * wp[1][j];
    qw2 += q[j] * wp[2][j];
    qb  += q[j] * bp[j];
  }
  #pragma unroll
  for (int off = 1; off < 8; off <<= 1) {
    qw0 += __shfl_xor(qw0, off, 64);
    qw1 += __shfl_xor(qw1, off, 64);
    qw2 += __shfl_xor(qw2, off, 64);
    qb  += __shfl_xor(qb, off, 64);
  }

  const float4 qp = posf4s[qs];
  const int* ip = idx + (size_t)qs * KNB;
  int nb[KNB];
  #pragma unroll
  for (int k = 0; k < KNB; ++k) nb[k] = base + ip[k];   // sorted row

  float sc[KNB];
  #pragma unroll
  for (int k = 0; k < KNB; ++k) {
    const size_t jg = (size_t)nb[k];
    const float* kr = Kb + jg * D_MODEL + lane * 8;
    float kk[8];
    *(float4*)&kk[0] = *(const float4*)(kr);
    *(float4*)&kk[4] = *(const float4*)(kr + 4);
    float pdot = 0.f;
    #pragma unroll
    for (int j2 = 0; j2 < 8; ++j2) pdot += q[j2] * kk[j2];
    #pragma unroll
    for (int off = 1; off < 8; off <<= 1) pdot += __shfl_xor(pdot, off, 64);
    const float4 np = posf4s[jg];
    sc[k] = (pdot + qw0 * (qp.x - np.x) + qw1 * (qp.y - np.y) +
             qw2 * (qp.z - np.z) + qb) * inv_t;
  }

  float m = sc[0];
  #pragma unroll
  for (int k = 1; k < KNB; ++k) m = fmaxf(m, sc[k]);
  float ssum = 0.f;
  #pragma unroll
  for (int k = 0; k < KNB; ++k) { sc[k] = expf(sc[k] - m); ssum += sc[k]; }
  const float inv_s = 1.f / ssum;

  float acc[8];
  #pragma unroll
  for (int j = 0; j < 8; ++j) acc[j] = 0.f;
  #pragma unroll
  for (int k = 0; k < KNB; ++k) {
    const float* vr = Vb + (size_t)nb[k] * D_MODEL + lane * 8;
    float vv[8];
    *(float4*)&vv[0] = *(const float4*)(vr);
    *(float4*)&vv[4] = *(const float4*)(vr + 4);
    const float wk = sc[k];
    #pragma unroll
    for (int j = 0; j < 8; ++j) acc[j] += wk * vv[j];
  }

  ushort4 hi0, hi1, lo0, lo1;
  unsigned short* oh = Aout + (size_t)qs * 1024 + lane * 8;
  unsigned short* ol = oh + 512;
  float a0 = acc[0] * inv_s, a1 = acc[1] * inv_s, a2 = acc[2] * inv_s, a3 = acc[3] * inv_s;
  float a4 = acc[4] * inv_s, a5 = acc[5] * inv_s, a6 = acc[6] * inv_s, a7 = acc[7] * inv_s;
  hi0.x = f2bf(a0); lo0.x = f2bf(a0 - bf2f(hi0.x));
  hi0.y = f2bf(a1); lo0.y = f2bf(a1 - bf2f(hi0.y));
  hi0.z = f2bf(a2); lo0.z = f2bf(a2 - bf2f(hi0.z));
  hi0.w = f2bf(a3); lo0.w = f2bf(a3 - bf2f(hi0.w));
  hi1.x = f2bf(a4); lo1.x = f2bf(a4 - bf2f(hi1.x));
  hi1.y = f2bf(a5); lo1.y = f2bf(a5 - bf2f(hi1.y));
  hi1.z = f2bf(a6); lo1.z = f2bf(a6 - bf2f(hi1.z));
  hi1.w = f2bf(a7); lo1.w = f2bf(a7 - bf2f(hi1.w));
  *(ushort4*)(oh) = hi0;
  *(ushort4*)(oh + 4) = hi1;
  *(ushort4*)(ol) = lo0;
  *(ushort4*)(ol + 4) = lo1;
}

// ---------------------------------------------------------------------------
// Kernel 5: LN over sorted proj rows, un-permuting on the final write.
// ---------------------------------------------------------------------------
__global__ __launch_bounds__(256) void ln_kernel(const float* __restrict__ proj,
                                                 const float* __restrict__ feat,
                                                 const int* __restrict__ perm,
                                                 const float* __restrict__ bo,
                                                 const float* __restrict__ gamma,
                                                 const float* __restrict__ beta,
                                                 float* __restrict__ out) {
  const int row = blockIdx.x * 4 + (threadIdx.x >> 6);
  const int lane = threadIdx.x & 63;
  const int orig = (row & ~4095) + perm[row];
  const float* pr = proj + (size_t)row * D_MODEL;
  const float* fr = feat + (size_t)orig * D_MODEL;

  float x[8];
  #pragma unroll
  for (int u = 0; u < 2; ++u) {
    const int c = u * 256 + lane * 4;
    const float4 p = *(const float4*)(pr + c);
    const float4 f = *(const float4*)(fr + c);
    const float4 bb = *(const float4*)(bo + c);
    x[u * 4 + 0] = p.x + bb.x + f.x;
    x[u * 4 + 1] = p.y + bb.y + f.y;
    x[u * 4 + 2] = p.z + bb.z + f.z;
    x[u * 4 + 3] = p.w + bb.w + f.w;
  }
  float sum = 0.f, sumsq = 0.f;
  #pragma unroll
  for (int i = 0; i < 8; ++i) { sum += x[i]; sumsq += x[i] * x[i]; }
  sum = wave_reduce_sum(sum);
  sumsq = wave_reduce_sum(sumsq);
  const float mu = sum * (1.f / D_MODEL);
  const float var = sumsq * (1.f / D_MODEL) - mu * mu;
  const float rstd = rsqrtf(var + LN_EPS);

  #pragma unroll
  for (int u = 0; u < 2; ++u) {
    const int c = u * 256 + lane * 4;
    const float4 g = *(const float4*)(gamma + c);
    const float4 bt = *(const float4*)(beta + c);
    float4 o;
    o.x = (x[u * 4 + 0] - mu) * rstd * g.x + bt.x;
    o.y = (x[u * 4 + 1] - mu) * rstd * g.y + bt.y;
    o.z = (x[u * 4 + 2] - mu) * rstd * g.z + bt.z;
    o.w = (x[u * 4 + 3] - mu) * rstd * g.w + bt.w;
    *(float4*)(out + (size_t)orig * D_MODEL + c) = o;
  }
}

// ---------------------------------------------------------------------------
extern "C" void kernel_launch(void* const* d_in, const int* in_sizes, int n_in,
                              void* d_out, int out_size, void* d_ws, size_t ws_size,
                              hipStream_t stream) {
  const float* positions = (const float*)d_in[0];
  const float* features  = (const float*)d_in[1];
  const float* Wq   = (const float*)d_in[3];
  const float* Wk   = (const float*)d_in[4];
  const float* Wv   = (const float*)d_in[5];
  const float* Wo   = (const float*)d_in[6];
  const float* bo   = (const float*)d_in[7];
  const float* Wpos = (const float*)d_in[8];
  const float* bpos = (const float*)d_in[9];
  const float* temp = (const float*)d_in[10];
  const float* gamma = (const float*)d_in[11];
  const float* beta  = (const float*)d_in[12];

  const int B = 2, N = 4096;
  const int BN = B * N;

  char* w = (char*)d_ws;
  float4* posf4  = (float4*)w;             w += (size_t)BN * sizeof(float4);
  float4* posf4s = (float4*)w;             w += (size_t)BN * sizeof(float4);
  int*    idxb   = (int*)w;                w += (size_t)BN * KNB * sizeof(int);
  int*    permb  = (int*)w;                w += (size_t)BN * sizeof(int);
  int*    histb  = (int*)w;                w += (size_t)B * NBUCK * sizeof(int);
  int*    offb   = (int*)w;                w += (size_t)B * NBUCK * sizeof(int);
  int*    buckb  = (int*)w;                w += (size_t)BN * sizeof(int);
  unsigned short* Abuf = (unsigned short*)w; w += (size_t)BN * 1024 * 2;
  unsigned short* BhQKV = (unsigned short*)w; w += (size_t)1536 * 512 * 2;
  unsigned short* BlQKV = (unsigned short*)w; w += (size_t)1536 * 512 * 2;
  unsigned short* BhO = (unsigned short*)w;   w += (size_t)512 * 512 * 2;
  unsigned short* BlO = (unsigned short*)w;   w += (size_t)512 * 512 * 2;
  float* Qb   = (float*)w;                 w += (size_t)BN * D_MODEL * sizeof(float);
  float* Kbuf = (float*)w;                 w += (size_t)BN * D_MODEL * sizeof(float);
  float* Vbuf = (float*)d_out;             // dead before LN overwrites d_out
  float* projb = Kbuf;                     // K dead after attention

  zero_hist_kernel<<<(B * NBUCK + 255) / 256, 256, 0, stream>>>(histb, B * NBUCK);
  bucket_kernel<<<(BN + 255) / 256, 256, 0, stream>>>(positions, posf4, histb,
                                                      buckb, BN);
  scan_kernel<<<B, 1024, 0, stream>>>(histb, offb);
  scatter_kernel<<<(BN + 255) / 256, 256, 0, stream>>>(posf4, buckb, offb,
                                                       permb, posf4s, BN);
  knn_kernel<<<BN, 64, 0, stream>>>(posf4s, idxb, N);

  conv_feat_kernel<<<(BN * D_MODEL / 4 + 255) / 256, 256, 0, stream>>>(
      features, permb, Abuf, BN * D_MODEL / 4);
  conv_w_kernel<<<4096, 256, 0, stream>>>(Wq, Wk, Wv, Wo, BhQKV, BlQKV, BhO, BlO);

  gemm_split_kernel<<<dim3(12, BN / 128), 256, 0, stream>>>(
      Abuf, BhQKV, BlQKV, Qb, Kbuf, Vbuf);

  attn_kernel<<<BN / 4, 256, 0, stream>>>(Qb, Kbuf, Vbuf, idxb,
                                          posf4s, Wpos, bpos, temp, Abuf,
                                          BN / 4);

  gemm_split_kernel<<<dim3(4, BN / 128), 256, 0, stream>>>(
      Abuf, BhO, BlO, projb, projb, projb);

  ln_kernel<<<BN / 4, 256, 0, stream>>>(projb, features, permb, bo, gamma, beta,
                                        (float*)d_out);
}

// Round 14
// 279.744 us; speedup vs baseline: 1.0400x; 1.0400x over previous
//
#include <hip/hip_runtime.h>
#include <cstdint>

#define D_MODEL 512
#define NUM_HEADS 8
#define D_HEAD 64
#define KNB 16
#define NBUCK 2048
#define KCAP 256
#define LN_EPS 1e-5f
#define FINF 3.4e38f

typedef __bf16 bf16x8v __attribute__((ext_vector_type(8)));
typedef float f32x4v __attribute__((ext_vector_type(4)));
typedef int i32x4 __attribute__((ext_vector_type(4)));
typedef const __attribute__((address_space(1))) unsigned int* gptr_t;
typedef __attribute__((address_space(3))) unsigned int* lptr_t;

__device__ __forceinline__ float wave_reduce_sum(float v) {
  #pragma unroll
  for (int off = 32; off > 0; off >>= 1) v += __shfl_xor(v, off, 64);
  return v;
}

// bf16 helpers (bit-level, round-to-nearest-even)
__device__ __forceinline__ unsigned short f2bf(float x) {
  unsigned int u = __float_as_uint(x);
  u = (u + 0x7fffu + ((u >> 16) & 1u)) >> 16;
  return (unsigned short)u;
}
__device__ __forceinline__ float bf2f(unsigned short h) {
  return __uint_as_float(((unsigned int)h) << 16);
}

// Morton helpers: bucketing quality only affects SPEED.
__device__ __forceinline__ unsigned spread3(unsigned x) {
  x &= 0x3FFu;
  x = (x | (x << 16)) & 0x030000FFu;
  x = (x | (x << 8))  & 0x0300F00Fu;
  x = (x | (x << 4))  & 0x030C30C3u;
  x = (x | (x << 2))  & 0x09249249u;
  return x;
}
__device__ __forceinline__ unsigned quant10(float v) {
  int q = (int)((v + 6.f) * (1023.f / 12.f));
  q = q < 0 ? 0 : (q > 1023 ? 1023 : q);
  return (unsigned)q;
}

// 64-lane bitonic sort ascending by (d, j) lexicographic (pairs distinct).
__device__ __forceinline__ void bitonic64(float& d, int& j, int lane) {
  #pragma unroll
  for (int k = 2; k <= 64; k <<= 1) {
    #pragma unroll
    for (int s = k >> 1; s > 0; s >>= 1) {
      const float od = __shfl_xor(d, s, 64);
      const int   oj = __shfl_xor(j, s, 64);
      const bool up = ((lane & k) == 0);
      const bool lower = ((lane & s) == 0);
      const bool oless = (od < d) || (od == d && oj < j);
      if ((lower == up) ? oless : !oless) { d = od; j = oj; }
    }
  }
}

// ---------------------------------------------------------------------------
// Kernel 0a: zero bucket histogram
// ---------------------------------------------------------------------------
__global__ void zero_hist_kernel(int* __restrict__ hist, int n) {
  const int t = blockIdx.x * blockDim.x + threadIdx.x;
  if (t < n) hist[t] = 0;
}

// ---------------------------------------------------------------------------
// Kernel 0b: pad pos -> float4, Morton bucket (top 11 bits), histogram.
// ---------------------------------------------------------------------------
__global__ void bucket_kernel(const float* __restrict__ pos,
                              float4* __restrict__ posf4,
                              int* __restrict__ hist,
                              int* __restrict__ bucketid, int total) {
  const int t = blockIdx.x * blockDim.x + threadIdx.x;
  if (t >= total) return;
  const float4 p = make_float4(pos[t * 3], pos[t * 3 + 1], pos[t * 3 + 2], 0.f);
  posf4[t] = p;
  const unsigned code = (spread3(quant10(p.z)) << 2) |
                        (spread3(quant10(p.y)) << 1) | spread3(quant10(p.x));
  const int bk = code >> 19;
  const int b = t >> 12;
  bucketid[t] = bk;
  atomicAdd(&hist[b * NBUCK + bk], 1);
}

// ---------------------------------------------------------------------------
// Kernel 0c: exclusive scan of 2048 buckets per batch (one block per batch).
// ---------------------------------------------------------------------------
__global__ __launch_bounds__(1024) void scan_kernel(const int* __restrict__ hist,
                                                    int* __restrict__ off) {
  __shared__ int lsum[16];
  const int b = blockIdx.x;
  const int tid = threadIdx.x;
  const int lane = tid & 63, wv = tid >> 6;
  const int h0 = hist[b * NBUCK + 2 * tid];
  const int h1 = hist[b * NBUCK + 2 * tid + 1];
  int v = h0 + h1;
  #pragma unroll
  for (int d = 1; d < 64; d <<= 1) {
    const int u = __shfl_up(v, d, 64);
    if (lane >= d) v += u;
  }
  if (lane == 63) lsum[wv] = v;
  __syncthreads();
  if (wv == 0) {
    int s = (lane < 16) ? lsum[lane] : 0;
    #pragma unroll
    for (int d = 1; d < 16; d <<= 1) {
      const int u = __shfl_up(s, d, 64);
      if (lane >= d) s += u;
    }
    if (lane < 16) lsum[lane] = s;
  }
  __syncthreads();
  const int base = (wv > 0) ? lsum[wv - 1] : 0;
  const int excl = v + base - (h0 + h1);
  off[b * NBUCK + 2 * tid] = excl;
  off[b * NBUCK + 2 * tid + 1] = excl + h0;
}

// ---------------------------------------------------------------------------
// Kernel 0d: scatter into bucket order.
// ---------------------------------------------------------------------------
__global__ void scatter_kernel(const float4* __restrict__ posf4,
                               const int* __restrict__ bucketid,
                               int* __restrict__ off,
                               int* __restrict__ perm,
                               float4* __restrict__ posf4s, int total) {
  const int t = blockIdx.x * blockDim.x + threadIdx.x;
  if (t >= total) return;
  const int b = t >> 12;
  const int i = t & 4095;
  const int slot = atomicAdd(&off[b * NBUCK + bucketid[t]], 1);
  perm[b * 4096 + slot] = i;
  posf4s[b * 4096 + slot] = posf4[t];
}

// ---------------------------------------------------------------------------
// Kernel 1: kNN — register-resident single scan + bitonic selection
// (unchanged from Round 12: measured fast, out of top-5).
// ---------------------------------------------------------------------------
__global__ __launch_bounds__(64) void knn_kernel(const float4* __restrict__ posf4s,
                                                 int* __restrict__ idx_out,
                                                 int N) {
  __shared__ float ldsD[KCAP];
  __shared__ int   ldsJ[KCAP];
  const int qs = blockIdx.x;           // global sorted id
  const int base = qs & ~4095;
  const int n = qs - base;             // batch-local sorted pos
  const int lane = threadIdx.x;
  const float4* pb = posf4s + base;
  const float4 qp = pb[n];

  float darr[64];
  float lmin = FINF;
  #pragma unroll
  for (int it = 0; it < 64; ++it) {
    const int j = (it << 6) + lane;
    const float4 p = pb[j];
    const float dx = qp.x - p.x, dy = qp.y - p.y, dz = qp.z - p.z;
    float d = dx * dx + dy * dy + dz * dz;
    if (j == n) d = FINF;
    darr[it] = d;
    lmin = fminf(lmin, d);
  }

  float tau;
  {
    float dm = lmin;
    int jm = lane;
    bitonic64(dm, jm, lane);
    tau = __shfl(dm, 15, 64);
  }

  int count = 0;
  #pragma unroll
  for (int it = 0; it < 64; ++it) {
    const float d = darr[it];
    const bool pred = (d <= tau);
    const unsigned long long mask = __ballot(pred);
    if (pred) {
      const int slot = count + __popcll(mask & ((1ull << lane) - 1ull));
      if (slot < KCAP) { ldsD[slot] = d; ldsJ[slot] = (it << 6) + lane; }
    }
    count += (int)__popcll(mask);
  }

  if (count <= KCAP) {
    float d = (lane < count) ? ldsD[lane] : FINF;
    int   jj = (lane < count) ? ldsJ[lane] : 0x40000000 + lane;
    bitonic64(d, jj, lane);
    for (int start = 64; start < count; start += 48) {
      if (lane >= 16) {
        const int src = start + lane - 16;
        d  = (src < count) ? ldsD[src] : FINF;
        jj = (src < count) ? ldsJ[src] : 0x40000000 + lane;
      }
      bitonic64(d, jj, lane);
    }
    if (lane < KNB) idx_out[qs * KNB + lane] = jj;
  } else {
    float dist[KNB];
    int nidx[KNB];
    #pragma unroll
    for (int t = 0; t < KNB; ++t) { dist[t] = FINF; nidx[t] = -1; }
    #pragma unroll
    for (int it = 0; it < 64; ++it) {
      const float d = darr[it];
      unsigned long long mask = __ballot(d <= tau);
      while (mask) {
        const int src = __builtin_ctzll(mask);
        mask &= (mask - 1);
        const float dd = __shfl(d, src, 64);
        const int jj = (it << 6) + src;
        if (dd < dist[KNB - 1]) {
          float dc = dd;
          int ic = jj;
          #pragma unroll
          for (int t = 0; t < KNB; ++t) {
            const bool sw = dc < dist[t];
            const float od = dist[t];
            const int oi = nidx[t];
            dist[t] = sw ? dc : od;
            nidx[t] = sw ? ic : oi;
            dc = sw ? od : dc;
            ic = sw ? oi : ic;
          }
        }
      }
    }
    #pragma unroll
    for (int t = 0; t < KNB; ++t) {
      const int v = nidx[t] < 0 ? 0 : nidx[t];
      if (lane == t) idx_out[qs * KNB + t] = v;
    }
  }
}

// ---------------------------------------------------------------------------
// Kernel 2a: features -> A' bf16 Mx1024 [hi|lo], rows gathered into sorted
// order.
// ---------------------------------------------------------------------------
__global__ __launch_bounds__(256) void conv_feat_kernel(const float* __restrict__ src,
                                                        const int* __restrict__ perm,
                                                        unsigned short* __restrict__ dst,
                                                        int total4) {
  const int t = blockIdx.x * blockDim.x + threadIdx.x;
  if (t >= total4) return;
  const int f = t * 4;
  const int row = f >> 9;
  const int col = f & 511;
  const int orig = (row & ~4095) + perm[row];
  const float4 v = *(const float4*)(src + (size_t)orig * 512 + col);
  ushort4 h, l;
  h.x = f2bf(v.x); l.x = f2bf(v.x - bf2f(h.x));
  h.y = f2bf(v.y); l.y = f2bf(v.y - bf2f(h.y));
  h.z = f2bf(v.z); l.z = f2bf(v.z - bf2f(h.z));
  h.w = f2bf(v.w); l.w = f2bf(v.w - bf2f(h.w));
  *(ushort4*)(dst + (size_t)row * 1024 + col) = h;
  *(ushort4*)(dst + (size_t)row * 1024 + 512 + col) = l;
}

// ---------------------------------------------------------------------------
// Kernel 2b: weights (512x512 fp32, W[k][n]) -> transposed split bf16
// ---------------------------------------------------------------------------
__global__ __launch_bounds__(256) void conv_w_kernel(const float* __restrict__ Wq,
                                                     const float* __restrict__ Wk,
                                                     const float* __restrict__ Wv,
                                                     const float* __restrict__ Wo,
                                                     unsigned short* __restrict__ BhQKV,
                                                     unsigned short* __restrict__ BlQKV,
                                                     unsigned short* __restrict__ BhO,
                                                     unsigned short* __restrict__ BlO) {
  const int wsel = blockIdx.x >> 10;
  const int i = ((blockIdx.x & 1023) << 8) + threadIdx.x;
  const int n = i >> 9;
  const int k = i & 511;
  const float* src = wsel == 0 ? Wq : wsel == 1 ? Wk : wsel == 2 ? Wv : Wo;
  unsigned short* dh = wsel < 3 ? BhQKV + (size_t)(wsel * 512 + n) * 512
                                : BhO + (size_t)n * 512;
  unsigned short* dl = wsel < 3 ? BlQKV + (size_t)(wsel * 512 + n) * 512
                                : BlO + (size_t)n * 512;
  const float w = src[(size_t)k * 512 + n];
  const unsigned short h = f2bf(w);
  dh[k] = h;
  dl[k] = f2bf(w - bf2f(h));
}

// ---------------------------------------------------------------------------
// Kernel 3: split-bf16 MFMA GEMM — Round 14: BK=64 (halve barrier count).
// r13 counters (MfmaUtil 24, VALU 8, HBM 31, occ 15, conflicts 0) = the
// barrier-drain stall: 32 barrier-pairs x ~900cyc vmcnt(0) drains dominate.
// BK=64 stages 128x64 tiles (AsH+AsL+Bs = 48 KB; 3 blocks/CU = grid's 3/CU,
// no occupancy loss) -> 64 MFMA per barrier in loop1, 32 in loop2; barrier
// pairs 32 -> 16. XOR swizzle generalized: slot quad = gq ^ (row & 7) ->
// reads hit each bank-group exactly 2x = free. Accumulation order per
// K-step unchanged (hi then lo) -> bitwise-identical output to r13.
// ---------------------------------------------------------------------------
__global__ __launch_bounds__(256) void gemm_split_kernel(
    const unsigned short* __restrict__ A,    // M x 1024  [hi|lo]
    const unsigned short* __restrict__ Bh,   // Ncols x 512
    const unsigned short* __restrict__ Bl,   // Ncols x 512
    float* __restrict__ C0, float* __restrict__ C1, float* __restrict__ C2) {
  __shared__ unsigned short AsH[8192];   // 128 rows x 64 halves (16 KB)
  __shared__ unsigned short AsL[8192];
  __shared__ unsigned short Bs[8192];

  const int tid = threadIdx.x;
  const int wid = tid >> 6;
  const int lane = tid & 63;
  const int lm = lane & 15;
  const int kq = lane >> 4;
  const int wr = wid >> 1;
  const int wc = wid & 1;
  const int bm = blockIdx.y, bn = blockIdx.x;
  const int rowA0 = bm * 128;
  const int rowB0 = bn * 128;

  f32x4v acc[4][4];
  #pragma unroll
  for (int mi = 0; mi < 4; ++mi)
    #pragma unroll
    for (int ni = 0; ni < 4; ++ni) {
      f32x4v z = {0.f, 0.f, 0.f, 0.f};
      acc[mi][ni] = z;
    }

  // stage a 128x64 tile (1024 16B chunks, 4/thread); slot (row, qs) holds
  // global quad qs ^ (row & 7). LDS dest stays linear (wave base + lane*16).
  auto stage64 = [&](unsigned short* dst, const unsigned short* gsrc,
                     int gstride, int grow0, int gk0) {
    #pragma unroll
    for (int i = 0; i < 4; ++i) {
      const int c = wid * 256 + i * 64 + lane;   // chunk 0..1023
      const int row = c >> 3;
      const int gq = (c & 7) ^ (row & 7);
      const unsigned short* ga =
          gsrc + (size_t)(grow0 + row) * gstride + gk0 + gq * 8;
      __builtin_amdgcn_global_load_lds((gptr_t)ga,
          (lptr_t)(dst + (size_t)(wid * 256 + i * 64) * 8), 16, 0, 0);
    }
  };
  // read global quad g of row from a swizzled 64-wide tile
  auto rd64 = [&](const unsigned short* src, int row, int g) -> i32x4 {
    const int sl = row * 8 + (g ^ (row & 7));
    return *(const i32x4*)(src + (size_t)sl * 8);
  };

  // ---- loop 1: (A_hi + A_lo) x B_hi, 64 MFMA per barrier ----
  for (int k0 = 0; k0 < 512; k0 += 64) {
    stage64(AsH, A, 1024, rowA0, k0);
    stage64(AsL, A, 1024, rowA0, 512 + k0);
    stage64(Bs, Bh, 512, rowB0, k0);
    __syncthreads();
    #pragma unroll
    for (int kh = 0; kh < 2; ++kh) {
      const int g = kh * 4 + kq;
      i32x4 ah[4], al[4], bb[4];
      #pragma unroll
      for (int mi = 0; mi < 4; ++mi) {
        ah[mi] = rd64(AsH, wr * 64 + mi * 16 + lm, g);
        al[mi] = rd64(AsL, wr * 64 + mi * 16 + lm, g);
      }
      #pragma unroll
      for (int ni = 0; ni < 4; ++ni)
        bb[ni] = rd64(Bs, wc * 64 + ni * 16 + lm, g);
      #pragma unroll
      for (int mi = 0; mi < 4; ++mi)
        #pragma unroll
        for (int ni = 0; ni < 4; ++ni) {
          acc[mi][ni] = __builtin_amdgcn_mfma_f32_16x16x32_bf16(
              __builtin_bit_cast(bf16x8v, ah[mi]),
              __builtin_bit_cast(bf16x8v, bb[ni]), acc[mi][ni], 0, 0, 0);
          acc[mi][ni] = __builtin_amdgcn_mfma_f32_16x16x32_bf16(
              __builtin_bit_cast(bf16x8v, al[mi]),
              __builtin_bit_cast(bf16x8v, bb[ni]), acc[mi][ni], 0, 0, 0);
        }
    }
    __syncthreads();
  }

  // ---- loop 2: A_hi x B_lo, 32 MFMA per barrier ----
  for (int k0 = 0; k0 < 512; k0 += 64) {
    stage64(AsH, A, 1024, rowA0, k0);
    stage64(Bs, Bl, 512, rowB0, k0);
    __syncthreads();
    #pragma unroll
    for (int kh = 0; kh < 2; ++kh) {
      const int g = kh * 4 + kq;
      i32x4 ah[4], bb[4];
      #pragma unroll
      for (int mi = 0; mi < 4; ++mi)
        ah[mi] = rd64(AsH, wr * 64 + mi * 16 + lm, g);
      #pragma unroll
      for (int ni = 0; ni < 4; ++ni)
        bb[ni] = rd64(Bs, wc * 64 + ni * 16 + lm, g);
      #pragma unroll
      for (int mi = 0; mi < 4; ++mi)
        #pragma unroll
        for (int ni = 0; ni < 4; ++ni)
          acc[mi][ni] = __builtin_amdgcn_mfma_f32_16x16x32_bf16(
              __builtin_bit_cast(bf16x8v, ah[mi]),
              __builtin_bit_cast(bf16x8v, bb[ni]), acc[mi][ni], 0, 0, 0);
    }
    __syncthreads();
  }

  const int sel = bn >> 2;
  float* __restrict__ Cb = sel == 0 ? C0 : sel == 1 ? C1 : C2;
  const int r0 = bm * 128 + wr * 64;
  const int c0 = ((bn & 3) << 7) + wc * 64;
  // C/D layout: col = lane&15, row = (lane>>4)*4 + reg   [m89/m91]
  #pragma unroll
  for (int mi = 0; mi < 4; ++mi)
    #pragma unroll
    for (int ni = 0; ni < 4; ++ni) {
      float* Cp = Cb + (size_t)(r0 + mi * 16 + kq * 4) * 512 + c0 + ni * 16 + lm;
      #pragma unroll
      for (int r = 0; r < 4; ++r) Cp[(size_t)r * 512] = acc[mi][ni][r];
    }
}

// ---------------------------------------------------------------------------
// Kernel 4: local attention, sorted order, XCD-swizzled blocks (unchanged).
// ---------------------------------------------------------------------------
__global__ __launch_bounds__(256) void attn_kernel(const float* __restrict__ Q,
                                                   const float* __restrict__ Kb,
                                                   const float* __restrict__ Vb,
                                                   const int* __restrict__ idx,
                                                   const float4* __restrict__ posf4s,
                                                   const float* __restrict__ Wpos,
                                                   const float* __restrict__ bpos,
                                                   const float* __restrict__ temperature,
                                                   unsigned short* __restrict__ Aout,
                                                   int nblocks) {
  int bid = blockIdx.x;
  bid = (bid & 7) * (nblocks >> 3) + (bid >> 3);        // XCD-contiguous
  const int qs = bid * 4 + (threadIdx.x >> 6);
  const int lane = threadIdx.x & 63;
  const int s = lane & 7;
  const int base = qs & ~4095;

  const float inv_t = 1.0f / temperature[0];

  float q[8];
  *(float4*)&q[0] = *(const float4*)(Q + (size_t)qs * D_MODEL + lane * 8);
  *(float4*)&q[4] = *(const float4*)(Q + (size_t)qs * D_MODEL + lane * 8 + 4);

  float wp[3][8], bp[8];
  #pragma unroll
  for (int c = 0; c < 3; ++c) {
    *(float4*)&wp[c][0] = *(const float4*)(Wpos + c * 128 + s * 8);
    *(float4*)&wp[c][4] = *(const float4*)(Wpos + c * 128 + s * 8 + 4);
  }
  *(float4*)&bp[0] = *(const float4*)(bpos + s * 8);
  *(float4*)&bp[4] = *(const float4*)(bpos + s * 8 + 4);
  float qw0 = 0.f, qw1 = 0.f, qw2 = 0.f, qb = 0.f;
  #pragma unroll
  for (int j = 0; j < 8; ++j) {
    qw0 += q[j] * wp[0][j];
    qw1 += q[j] * wp[1][j];
    qw2 += q[j] * wp[2][j];
    qb  += q[j] * bp[j];
  }
  #pragma unroll
  for (int off = 1; off < 8; off <<= 1) {
    qw0 += __shfl_xor(qw0, off, 64);
    qw1 += __shfl_xor(qw1, off, 64);
    qw2 += __shfl_xor(qw2, off, 64);
    qb  += __shfl_xor(qb, off, 64);
  }

  const float4 qp = posf4s[qs];
  const int* ip = idx + (size_t)qs * KNB;
  int nb[KNB];
  #pragma unroll
  for (int k = 0; k < KNB; ++k) nb[k] = base + ip[k];   // sorted row

  float sc[KNB];
  #pragma unroll
  for (int k = 0; k < KNB; ++k) {
    const size_t jg = (size_t)nb[k];
    const float* kr = Kb + jg * D_MODEL + lane * 8;
    float kk[8];
    *(float4*)&kk[0] = *(const float4*)(kr);
    *(float4*)&kk[4] = *(const float4*)(kr + 4);
    float pdot = 0.f;
    #pragma unroll
    for (int j2 = 0; j2 < 8; ++j2) pdot += q[j2] * kk[j2];
    #pragma unroll
    for (int off = 1; off < 8; off <<= 1) pdot += __shfl_xor(pdot, off, 64);
    const float4 np = posf4s[jg];
    sc[k] = (pdot + qw0 * (qp.x - np.x) + qw1 * (qp.y - np.y) +
             qw2 * (qp.z - np.z) + qb) * inv_t;
  }

  float m = sc[0];
  #pragma unroll
  for (int k = 1; k < KNB; ++k) m = fmaxf(m, sc[k]);
  float ssum = 0.f;
  #pragma unroll
  for (int k = 0; k < KNB; ++k) { sc[k] = expf(sc[k] - m); ssum += sc[k]; }
  const float inv_s = 1.f / ssum;

  float acc[8];
  #pragma unroll
  for (int j = 0; j < 8; ++j) acc[j] = 0.f;
  #pragma unroll
  for (int k = 0; k < KNB; ++k) {
    const float* vr = Vb + (size_t)nb[k] * D_MODEL + lane * 8;
    float vv[8];
    *(float4*)&vv[0] = *(const float4*)(vr);
    *(float4*)&vv[4] = *(const float4*)(vr + 4);
    const float wk = sc[k];
    #pragma unroll
    for (int j = 0; j < 8; ++j) acc[j] += wk * vv[j];
  }

  ushort4 hi0, hi1, lo0, lo1;
  unsigned short* oh = Aout + (size_t)qs * 1024 + lane * 8;
  unsigned short* ol = oh + 512;
  float a0 = acc[0] * inv_s, a1 = acc[1] * inv_s, a2 = acc[2] * inv_s, a3 = acc[3] * inv_s;
  float a4 = acc[4] * inv_s, a5 = acc[5] * inv_s, a6 = acc[6] * inv_s, a7 = acc[7] * inv_s;
  hi0.x = f2bf(a0); lo0.x = f2bf(a0 - bf2f(hi0.x));
  hi0.y = f2bf(a1); lo0.y = f2bf(a1 - bf2f(hi0.y));
  hi0.z = f2bf(a2); lo0.z = f2bf(a2 - bf2f(hi0.z));
  hi0.w = f2bf(a3); lo0.w = f2bf(a3 - bf2f(hi0.w));
  hi1.x = f2bf(a4); lo1.x = f2bf(a4 - bf2f(hi1.x));
  hi1.y = f2bf(a5); lo1.y = f2bf(a5 - bf2f(hi1.y));
  hi1.z = f2bf(a6); lo1.z = f2bf(a6 - bf2f(hi1.z));
  hi1.w = f2bf(a7); lo1.w = f2bf(a7 - bf2f(hi1.w));
  *(ushort4*)(oh) = hi0;
  *(ushort4*)(oh + 4) = hi1;
  *(ushort4*)(ol) = lo0;
  *(ushort4*)(ol + 4) = lo1;
}

// ---------------------------------------------------------------------------
// Kernel 5: LN over sorted proj rows, un-permuting on the final write.
// ---------------------------------------------------------------------------
__global__ __launch_bounds__(256) void ln_kernel(const float* __restrict__ proj,
                                                 const float* __restrict__ feat,
                                                 const int* __restrict__ perm,
                                                 const float* __restrict__ bo,
                                                 const float* __restrict__ gamma,
                                                 const float* __restrict__ beta,
                                                 float* __restrict__ out) {
  const int row = blockIdx.x * 4 + (threadIdx.x >> 6);
  const int lane = threadIdx.x & 63;
  const int orig = (row & ~4095) + perm[row];
  const float* pr = proj + (size_t)row * D_MODEL;
  const float* fr = feat + (size_t)orig * D_MODEL;

  float x[8];
  #pragma unroll
  for (int u = 0; u < 2; ++u) {
    const int c = u * 256 + lane * 4;
    const float4 p = *(const float4*)(pr + c);
    const float4 f = *(const float4*)(fr + c);
    const float4 bb = *(const float4*)(bo + c);
    x[u * 4 + 0] = p.x + bb.x + f.x;
    x[u * 4 + 1] = p.y + bb.y + f.y;
    x[u * 4 + 2] = p.z + bb.z + f.z;
    x[u * 4 + 3] = p.w + bb.w + f.w;
  }
  float sum = 0.f, sumsq = 0.f;
  #pragma unroll
  for (int i = 0; i < 8; ++i) { sum += x[i]; sumsq += x[i] * x[i]; }
  sum = wave_reduce_sum(sum);
  sumsq = wave_reduce_sum(sumsq);
  const float mu = sum * (1.f / D_MODEL);
  const float var = sumsq * (1.f / D_MODEL) - mu * mu;
  const float rstd = rsqrtf(var + LN_EPS);

  #pragma unroll
  for (int u = 0; u < 2; ++u) {
    const int c = u * 256 + lane * 4;
    const float4 g = *(const float4*)(gamma + c);
    const float4 bt = *(const float4*)(beta + c);
    float4 o;
    o.x = (x[u * 4 + 0] - mu) * rstd * g.x + bt.x;
    o.y = (x[u * 4 + 1] - mu) * rstd * g.y + bt.y;
    o.z = (x[u * 4 + 2] - mu) * rstd * g.z + bt.z;
    o.w = (x[u * 4 + 3] - mu) * rstd * g.w + bt.w;
    *(float4*)(out + (size_t)orig * D_MODEL + c) = o;
  }
}

// ---------------------------------------------------------------------------
extern "C" void kernel_launch(void* const* d_in, const int* in_sizes, int n_in,
                              void* d_out, int out_size, void* d_ws, size_t ws_size,
                              hipStream_t stream) {
  const float* positions = (const float*)d_in[0];
  const float* features  = (const float*)d_in[1];
  const float* Wq   = (const float*)d_in[3];
  const float* Wk   = (const float*)d_in[4];
  const float* Wv   = (const float*)d_in[5];
  const float* Wo   = (const float*)d_in[6];
  const float* bo   = (const float*)d_in[7];
  const float* Wpos = (const float*)d_in[8];
  const float* bpos = (const float*)d_in[9];
  const float* temp = (const float*)d_in[10];
  const float* gamma = (const float*)d_in[11];
  const float* beta  = (const float*)d_in[12];

  const int B = 2, N = 4096;
  const int BN = B * N;

  char* w = (char*)d_ws;
  float4* posf4  = (float4*)w;             w += (size_t)BN * sizeof(float4);
  float4* posf4s = (float4*)w;             w += (size_t)BN * sizeof(float4);
  int*    idxb   = (int*)w;                w += (size_t)BN * KNB * sizeof(int);
  int*    permb  = (int*)w;                w += (size_t)BN * sizeof(int);
  int*    histb  = (int*)w;                w += (size_t)B * NBUCK * sizeof(int);
  int*    offb   = (int*)w;                w += (size_t)B * NBUCK * sizeof(int);
  int*    buckb  = (int*)w;                w += (size_t)BN * sizeof(int);
  unsigned short* Abuf = (unsigned short*)w; w += (size_t)BN * 1024 * 2;
  unsigned short* BhQKV = (unsigned short*)w; w += (size_t)1536 * 512 * 2;
  unsigned short* BlQKV = (unsigned short*)w; w += (size_t)1536 * 512 * 2;
  unsigned short* BhO = (unsigned short*)w;   w += (size_t)512 * 512 * 2;
  unsigned short* BlO = (unsigned short*)w;   w += (size_t)512 * 512 * 2;
  float* Qb   = (float*)w;                 w += (size_t)BN * D_MODEL * sizeof(float);
  float* Kbuf = (float*)w;                 w += (size_t)BN * D_MODEL * sizeof(float);
  float* Vbuf = (float*)d_out;             // dead before LN overwrites d_out
  float* projb = Kbuf;                     // K dead after attention

  zero_hist_kernel<<<(B * NBUCK + 255) / 256, 256, 0, stream>>>(histb, B * NBUCK);
  bucket_kernel<<<(BN + 255) / 256, 256, 0, stream>>>(positions, posf4, histb,
                                                      buckb, BN);
  scan_kernel<<<B, 1024, 0, stream>>>(histb, offb);
  scatter_kernel<<<(BN + 255) / 256, 256, 0, stream>>>(posf4, buckb, offb,
                                                       permb, posf4s, BN);
  knn_kernel<<<BN, 64, 0, stream>>>(posf4s, idxb, N);

  conv_feat_kernel<<<(BN * D_MODEL / 4 + 255) / 256, 256, 0, stream>>>(
      features, permb, Abuf, BN * D_MODEL / 4);
  conv_w_kernel<<<4096, 256, 0, stream>>>(Wq, Wk, Wv, Wo, BhQKV, BlQKV, BhO, BlO);

  gemm_split_kernel<<<dim3(12, BN / 128), 256, 0, stream>>>(
      Abuf, BhQKV, BlQKV, Qb, Kbuf, Vbuf);

  attn_kernel<<<BN / 4, 256, 0, stream>>>(Qb, Kbuf, Vbuf, idxb,
                                          posf4s, Wpos, bpos, temp, Abuf,
                                          BN / 4);

  gemm_split_kernel<<<dim3(4, BN / 128), 256, 0, stream>>>(
      Abuf, BhO, BlO, projb, projb, projb);

  ln_kernel<<<BN / 4, 256, 0, stream>>>(projb, features, permb, bo, gamma, beta,
                                        (float*)d_out);
}

// Round 15
// 269.493 us; speedup vs baseline: 1.0796x; 1.0380x over previous
//
#include <hip/hip_runtime.h>
#include <cstdint>

#define D_MODEL 512
#define NUM_HEADS 8
#define D_HEAD 64
#define KNB 16
#define NBUCK 2048
#define KCAP 256
#define LN_EPS 1e-5f
#define FINF 3.4e38f

typedef __bf16 bf16x8v __attribute__((ext_vector_type(8)));
typedef float f32x4v __attribute__((ext_vector_type(4)));
typedef int i32x4 __attribute__((ext_vector_type(4)));
typedef const __attribute__((address_space(1))) unsigned int* gptr_t;
typedef __attribute__((address_space(3))) unsigned int* lptr_t;

__device__ __forceinline__ float wave_reduce_sum(float v) {
  #pragma unroll
  for (int off = 32; off > 0; off >>= 1) v += __shfl_xor(v, off, 64);
  return v;
}

// bf16 helpers (bit-level, round-to-nearest-even)
__device__ __forceinline__ unsigned short f2bf(float x) {
  unsigned int u = __float_as_uint(x);
  u = (u + 0x7fffu + ((u >> 16) & 1u)) >> 16;
  return (unsigned short)u;
}
__device__ __forceinline__ float bf2f(unsigned short h) {
  return __uint_as_float(((unsigned int)h) << 16);
}

// Morton helpers: bucketing quality only affects SPEED.
__device__ __forceinline__ unsigned spread3(unsigned x) {
  x &= 0x3FFu;
  x = (x | (x << 16)) & 0x030000FFu;
  x = (x | (x << 8))  & 0x0300F00Fu;
  x = (x | (x << 4))  & 0x030C30C3u;
  x = (x | (x << 2))  & 0x09249249u;
  return x;
}
__device__ __forceinline__ unsigned quant10(float v) {
  int q = (int)((v + 6.f) * (1023.f / 12.f));
  q = q < 0 ? 0 : (q > 1023 ? 1023 : q);
  return (unsigned)q;
}

// 64-lane bitonic sort ascending by (d, j) lexicographic (pairs distinct).
__device__ __forceinline__ void bitonic64(float& d, int& j, int lane) {
  #pragma unroll
  for (int k = 2; k <= 64; k <<= 1) {
    #pragma unroll
    for (int s = k >> 1; s > 0; s >>= 1) {
      const float od = __shfl_xor(d, s, 64);
      const int   oj = __shfl_xor(j, s, 64);
      const bool up = ((lane & k) == 0);
      const bool lower = ((lane & s) == 0);
      const bool oless = (od < d) || (od == d && oj < j);
      if ((lower == up) ? oless : !oless) { d = od; j = oj; }
    }
  }
}

// ---------------------------------------------------------------------------
// Kernel 0a: zero bucket histogram
// ---------------------------------------------------------------------------
__global__ void zero_hist_kernel(int* __restrict__ hist, int n) {
  const int t = blockIdx.x * blockDim.x + threadIdx.x;
  if (t < n) hist[t] = 0;
}

// ---------------------------------------------------------------------------
// Kernel 0b: pad pos -> float4, Morton bucket (top 11 bits), histogram.
// ---------------------------------------------------------------------------
__global__ void bucket_kernel(const float* __restrict__ pos,
                              float4* __restrict__ posf4,
                              int* __restrict__ hist,
                              int* __restrict__ bucketid, int total) {
  const int t = blockIdx.x * blockDim.x + threadIdx.x;
  if (t >= total) return;
  const float4 p = make_float4(pos[t * 3], pos[t * 3 + 1], pos[t * 3 + 2], 0.f);
  posf4[t] = p;
  const unsigned code = (spread3(quant10(p.z)) << 2) |
                        (spread3(quant10(p.y)) << 1) | spread3(quant10(p.x));
  const int bk = code >> 19;
  const int b = t >> 12;
  bucketid[t] = bk;
  atomicAdd(&hist[b * NBUCK + bk], 1);
}

// ---------------------------------------------------------------------------
// Kernel 0c: exclusive scan of 2048 buckets per batch (one block per batch).
// ---------------------------------------------------------------------------
__global__ __launch_bounds__(1024) void scan_kernel(const int* __restrict__ hist,
                                                    int* __restrict__ off) {
  __shared__ int lsum[16];
  const int b = blockIdx.x;
  const int tid = threadIdx.x;
  const int lane = tid & 63, wv = tid >> 6;
  const int h0 = hist[b * NBUCK + 2 * tid];
  const int h1 = hist[b * NBUCK + 2 * tid + 1];
  int v = h0 + h1;
  #pragma unroll
  for (int d = 1; d < 64; d <<= 1) {
    const int u = __shfl_up(v, d, 64);
    if (lane >= d) v += u;
  }
  if (lane == 63) lsum[wv] = v;
  __syncthreads();
  if (wv == 0) {
    int s = (lane < 16) ? lsum[lane] : 0;
    #pragma unroll
    for (int d = 1; d < 16; d <<= 1) {
      const int u = __shfl_up(s, d, 64);
      if (lane >= d) s += u;
    }
    if (lane < 16) lsum[lane] = s;
  }
  __syncthreads();
  const int base = (wv > 0) ? lsum[wv - 1] : 0;
  const int excl = v + base - (h0 + h1);
  off[b * NBUCK + 2 * tid] = excl;
  off[b * NBUCK + 2 * tid + 1] = excl + h0;
}

// ---------------------------------------------------------------------------
// Kernel 0d: scatter into bucket order.
// ---------------------------------------------------------------------------
__global__ void scatter_kernel(const float4* __restrict__ posf4,
                               const int* __restrict__ bucketid,
                               int* __restrict__ off,
                               int* __restrict__ perm,
                               float4* __restrict__ posf4s, int total) {
  const int t = blockIdx.x * blockDim.x + threadIdx.x;
  if (t >= total) return;
  const int b = t >> 12;
  const int i = t & 4095;
  const int slot = atomicAdd(&off[b * NBUCK + bucketid[t]], 1);
  perm[b * 4096 + slot] = i;
  posf4s[b * 4096 + slot] = posf4[t];
}

// ---------------------------------------------------------------------------
// Kernel 1: kNN — register-resident single scan + bitonic selection
// (unchanged from Round 12: measured fast, out of top-5).
// ---------------------------------------------------------------------------
__global__ __launch_bounds__(64) void knn_kernel(const float4* __restrict__ posf4s,
                                                 int* __restrict__ idx_out,
                                                 int N) {
  __shared__ float ldsD[KCAP];
  __shared__ int   ldsJ[KCAP];
  const int qs = blockIdx.x;           // global sorted id
  const int base = qs & ~4095;
  const int n = qs - base;             // batch-local sorted pos
  const int lane = threadIdx.x;
  const float4* pb = posf4s + base;
  const float4 qp = pb[n];

  float darr[64];
  float lmin = FINF;
  #pragma unroll
  for (int it = 0; it < 64; ++it) {
    const int j = (it << 6) + lane;
    const float4 p = pb[j];
    const float dx = qp.x - p.x, dy = qp.y - p.y, dz = qp.z - p.z;
    float d = dx * dx + dy * dy + dz * dz;
    if (j == n) d = FINF;
    darr[it] = d;
    lmin = fminf(lmin, d);
  }

  float tau;
  {
    float dm = lmin;
    int jm = lane;
    bitonic64(dm, jm, lane);
    tau = __shfl(dm, 15, 64);
  }

  int count = 0;
  #pragma unroll
  for (int it = 0; it < 64; ++it) {
    const float d = darr[it];
    const bool pred = (d <= tau);
    const unsigned long long mask = __ballot(pred);
    if (pred) {
      const int slot = count + __popcll(mask & ((1ull << lane) - 1ull));
      if (slot < KCAP) { ldsD[slot] = d; ldsJ[slot] = (it << 6) + lane; }
    }
    count += (int)__popcll(mask);
  }

  if (count <= KCAP) {
    float d = (lane < count) ? ldsD[lane] : FINF;
    int   jj = (lane < count) ? ldsJ[lane] : 0x40000000 + lane;
    bitonic64(d, jj, lane);
    for (int start = 64; start < count; start += 48) {
      if (lane >= 16) {
        const int src = start + lane - 16;
        d  = (src < count) ? ldsD[src] : FINF;
        jj = (src < count) ? ldsJ[src] : 0x40000000 + lane;
      }
      bitonic64(d, jj, lane);
    }
    if (lane < KNB) idx_out[qs * KNB + lane] = jj;
  } else {
    float dist[KNB];
    int nidx[KNB];
    #pragma unroll
    for (int t = 0; t < KNB; ++t) { dist[t] = FINF; nidx[t] = -1; }
    #pragma unroll
    for (int it = 0; it < 64; ++it) {
      const float d = darr[it];
      unsigned long long mask = __ballot(d <= tau);
      while (mask) {
        const int src = __builtin_ctzll(mask);
        mask &= (mask - 1);
        const float dd = __shfl(d, src, 64);
        const int jj = (it << 6) + src;
        if (dd < dist[KNB - 1]) {
          float dc = dd;
          int ic = jj;
          #pragma unroll
          for (int t = 0; t < KNB; ++t) {
            const bool sw = dc < dist[t];
            const float od = dist[t];
            const int oi = nidx[t];
            dist[t] = sw ? dc : od;
            nidx[t] = sw ? ic : oi;
            dc = sw ? od : dc;
            ic = sw ? oi : ic;
          }
        }
      }
    }
    #pragma unroll
    for (int t = 0; t < KNB; ++t) {
      const int v = nidx[t] < 0 ? 0 : nidx[t];
      if (lane == t) idx_out[qs * KNB + t] = v;
    }
  }
}

// ---------------------------------------------------------------------------
// Kernel 2a: features -> A' bf16 Mx1024 [hi|lo], rows gathered into sorted
// order.
// ---------------------------------------------------------------------------
__global__ __launch_bounds__(256) void conv_feat_kernel(const float* __restrict__ src,
                                                        const int* __restrict__ perm,
                                                        unsigned short* __restrict__ dst,
                                                        int total4) {
  const int t = blockIdx.x * blockDim.x + threadIdx.x;
  if (t >= total4) return;
  const int f = t * 4;
  const int row = f >> 9;
  const int col = f & 511;
  const int orig = (row & ~4095) + perm[row];
  const float4 v = *(const float4*)(src + (size_t)orig * 512 + col);
  ushort4 h, l;
  h.x = f2bf(v.x); l.x = f2bf(v.x - bf2f(h.x));
  h.y = f2bf(v.y); l.y = f2bf(v.y - bf2f(h.y));
  h.z = f2bf(v.z); l.z = f2bf(v.z - bf2f(h.z));
  h.w = f2bf(v.w); l.w = f2bf(v.w - bf2f(h.w));
  *(ushort4*)(dst + (size_t)row * 1024 + col) = h;
  *(ushort4*)(dst + (size_t)row * 1024 + 512 + col) = l;
}

// ---------------------------------------------------------------------------
// Kernel 2b: weights (512x512 fp32, W[k][n]) -> transposed split bf16
// ---------------------------------------------------------------------------
__global__ __launch_bounds__(256) void conv_w_kernel(const float* __restrict__ Wq,
                                                     const float* __restrict__ Wk,
                                                     const float* __restrict__ Wv,
                                                     const float* __restrict__ Wo,
                                                     unsigned short* __restrict__ BhQKV,
                                                     unsigned short* __restrict__ BlQKV,
                                                     unsigned short* __restrict__ BhO,
                                                     unsigned short* __restrict__ BlO) {
  const int wsel = blockIdx.x >> 10;
  const int i = ((blockIdx.x & 1023) << 8) + threadIdx.x;
  const int n = i >> 9;
  const int k = i & 511;
  const float* src = wsel == 0 ? Wq : wsel == 1 ? Wk : wsel == 2 ? Wv : Wo;
  unsigned short* dh = wsel < 3 ? BhQKV + (size_t)(wsel * 512 + n) * 512
                                : BhO + (size_t)n * 512;
  unsigned short* dl = wsel < 3 ? BlQKV + (size_t)(wsel * 512 + n) * 512
                                : BlO + (size_t)n * 512;
  const float w = src[(size_t)k * 512 + n];
  const unsigned short h = f2bf(w);
  dh[k] = h;
  dl[k] = f2bf(w - bf2f(h));
}

// ---------------------------------------------------------------------------
// Kernel 3: split-bf16 MFMA GEMM — Round 15: XCD-aware grid swizzle.
// r14 counters: FETCH 101 MB vs ~21 MB ideal. Cause: (12 x 64) grid with
// x-fastest dispatch puts the 12 blocks sharing an A-tile round-robin on 8
// different XCDs -> each per-XCD L2 re-fetches A (16.7 MB x 8 ~ 134 MB) and
// the barrier drains wait on HBM latency (~900cyc) instead of L2 (~200cyc).
// Fix: 1D grid; bid -> xcd = bid&7, i = bid>>3; bm = xcd*8 + i/nbn,
// bn = i%nbn. Each XCD owns 8 contiguous bm rows x all bn: A-rows 2 MB +
// B 1.6 MB < 4 MB XCD L2 -> A fetched ~once per XCD. Heuristic only —
// correctness is mapping-independent. BK=64 + XOR swizzle kept from r14.
// ---------------------------------------------------------------------------
__global__ __launch_bounds__(256) void gemm_split_kernel(
    const unsigned short* __restrict__ A,    // M x 1024  [hi|lo]
    const unsigned short* __restrict__ Bh,   // Ncols x 512
    const unsigned short* __restrict__ Bl,   // Ncols x 512
    float* __restrict__ C0, float* __restrict__ C1, float* __restrict__ C2,
    int nbn) {
  __shared__ unsigned short AsH[8192];   // 128 rows x 64 halves (16 KB)
  __shared__ unsigned short AsL[8192];
  __shared__ unsigned short Bs[8192];

  const int tid = threadIdx.x;
  const int wid = tid >> 6;
  const int lane = tid & 63;
  const int lm = lane & 15;
  const int kq = lane >> 4;
  const int wr = wid >> 1;
  const int wc = wid & 1;
  // XCD-aware decomposition (round-robin bid->XCD assumed; perf-only)
  const int bid = blockIdx.x;
  const int xcd = bid & 7;
  const int i = bid >> 3;
  const int bm = xcd * 8 + i / nbn;
  const int bn = i % nbn;
  const int rowA0 = bm * 128;
  const int rowB0 = bn * 128;

  f32x4v acc[4][4];
  #pragma unroll
  for (int mi = 0; mi < 4; ++mi)
    #pragma unroll
    for (int ni = 0; ni < 4; ++ni) {
      f32x4v z = {0.f, 0.f, 0.f, 0.f};
      acc[mi][ni] = z;
    }

  // stage a 128x64 tile (1024 16B chunks, 4/thread); slot (row, qs) holds
  // global quad qs ^ (row & 7). LDS dest stays linear (wave base + lane*16).
  auto stage64 = [&](unsigned short* dst, const unsigned short* gsrc,
                     int gstride, int grow0, int gk0) {
    #pragma unroll
    for (int i2 = 0; i2 < 4; ++i2) {
      const int c = wid * 256 + i2 * 64 + lane;   // chunk 0..1023
      const int row = c >> 3;
      const int gq = (c & 7) ^ (row & 7);
      const unsigned short* ga =
          gsrc + (size_t)(grow0 + row) * gstride + gk0 + gq * 8;
      __builtin_amdgcn_global_load_lds((gptr_t)ga,
          (lptr_t)(dst + (size_t)(wid * 256 + i2 * 64) * 8), 16, 0, 0);
    }
  };
  // read global quad g of row from a swizzled 64-wide tile
  auto rd64 = [&](const unsigned short* src, int row, int g) -> i32x4 {
    const int sl = row * 8 + (g ^ (row & 7));
    return *(const i32x4*)(src + (size_t)sl * 8);
  };

  // ---- loop 1: (A_hi + A_lo) x B_hi, 64 MFMA per barrier ----
  for (int k0 = 0; k0 < 512; k0 += 64) {
    stage64(AsH, A, 1024, rowA0, k0);
    stage64(AsL, A, 1024, rowA0, 512 + k0);
    stage64(Bs, Bh, 512, rowB0, k0);
    __syncthreads();
    #pragma unroll
    for (int kh = 0; kh < 2; ++kh) {
      const int g = kh * 4 + kq;
      i32x4 ah[4], al[4], bb[4];
      #pragma unroll
      for (int mi = 0; mi < 4; ++mi) {
        ah[mi] = rd64(AsH, wr * 64 + mi * 16 + lm, g);
        al[mi] = rd64(AsL, wr * 64 + mi * 16 + lm, g);
      }
      #pragma unroll
      for (int ni = 0; ni < 4; ++ni)
        bb[ni] = rd64(Bs, wc * 64 + ni * 16 + lm, g);
      #pragma unroll
      for (int mi = 0; mi < 4; ++mi)
        #pragma unroll
        for (int ni = 0; ni < 4; ++ni) {
          acc[mi][ni] = __builtin_amdgcn_mfma_f32_16x16x32_bf16(
              __builtin_bit_cast(bf16x8v, ah[mi]),
              __builtin_bit_cast(bf16x8v, bb[ni]), acc[mi][ni], 0, 0, 0);
          acc[mi][ni] = __builtin_amdgcn_mfma_f32_16x16x32_bf16(
              __builtin_bit_cast(bf16x8v, al[mi]),
              __builtin_bit_cast(bf16x8v, bb[ni]), acc[mi][ni], 0, 0, 0);
        }
    }
    __syncthreads();
  }

  // ---- loop 2: A_hi x B_lo, 32 MFMA per barrier ----
  for (int k0 = 0; k0 < 512; k0 += 64) {
    stage64(AsH, A, 1024, rowA0, k0);
    stage64(Bs, Bl, 512, rowB0, k0);
    __syncthreads();
    #pragma unroll
    for (int kh = 0; kh < 2; ++kh) {
      const int g = kh * 4 + kq;
      i32x4 ah[4], bb[4];
      #pragma unroll
      for (int mi = 0; mi < 4; ++mi)
        ah[mi] = rd64(AsH, wr * 64 + mi * 16 + lm, g);
      #pragma unroll
      for (int ni = 0; ni < 4; ++ni)
        bb[ni] = rd64(Bs, wc * 64 + ni * 16 + lm, g);
      #pragma unroll
      for (int mi = 0; mi < 4; ++mi)
        #pragma unroll
        for (int ni = 0; ni < 4; ++ni)
          acc[mi][ni] = __builtin_amdgcn_mfma_f32_16x16x32_bf16(
              __builtin_bit_cast(bf16x8v, ah[mi]),
              __builtin_bit_cast(bf16x8v, bb[ni]), acc[mi][ni], 0, 0, 0);
    }
    __syncthreads();
  }

  const int sel = bn >> 2;
  float* __restrict__ Cb = sel == 0 ? C0 : sel == 1 ? C1 : C2;
  const int r0 = bm * 128 + wr * 64;
  const int c0 = ((bn & 3) << 7) + wc * 64;
  // C/D layout: col = lane&15, row = (lane>>4)*4 + reg   [m89/m91]
  #pragma unroll
  for (int mi = 0; mi < 4; ++mi)
    #pragma unroll
    for (int ni = 0; ni < 4; ++ni) {
      float* Cp = Cb + (size_t)(r0 + mi * 16 + kq * 4) * 512 + c0 + ni * 16 + lm;
      #pragma unroll
      for (int r = 0; r < 4; ++r) Cp[(size_t)r * 512] = acc[mi][ni][r];
    }
}

// ---------------------------------------------------------------------------
// Kernel 4: local attention, sorted order, XCD-swizzled blocks (unchanged).
// ---------------------------------------------------------------------------
__global__ __launch_bounds__(256) void attn_kernel(const float* __restrict__ Q,
                                                   const float* __restrict__ Kb,
                                                   const float* __restrict__ Vb,
                                                   const int* __restrict__ idx,
                                                   const float4* __restrict__ posf4s,
                                                   const float* __restrict__ Wpos,
                                                   const float* __restrict__ bpos,
                                                   const float* __restrict__ temperature,
                                                   unsigned short* __restrict__ Aout,
                                                   int nblocks) {
  int bid = blockIdx.x;
  bid = (bid & 7) * (nblocks >> 3) + (bid >> 3);        // XCD-contiguous
  const int qs = bid * 4 + (threadIdx.x >> 6);
  const int lane = threadIdx.x & 63;
  const int s = lane & 7;
  const int base = qs & ~4095;

  const float inv_t = 1.0f / temperature[0];

  float q[8];
  *(float4*)&q[0] = *(const float4*)(Q + (size_t)qs * D_MODEL + lane * 8);
  *(float4*)&q[4] = *(const float4*)(Q + (size_t)qs * D_MODEL + lane * 8 + 4);

  float wp[3][8], bp[8];
  #pragma unroll
  for (int c = 0; c < 3; ++c) {
    *(float4*)&wp[c][0] = *(const float4*)(Wpos + c * 128 + s * 8);
    *(float4*)&wp[c][4] = *(const float4*)(Wpos + c * 128 + s * 8 + 4);
  }
  *(float4*)&bp[0] = *(const float4*)(bpos + s * 8);
  *(float4*)&bp[4] = *(const float4*)(bpos + s * 8 + 4);
  float qw0 = 0.f, qw1 = 0.f, qw2 = 0.f, qb = 0.f;
  #pragma unroll
  for (int j = 0; j < 8; ++j) {
    qw0 += q[j] * wp[0][j];
    qw1 += q[j] * wp[1][j];
    qw2 += q[j] * wp[2][j];
    qb  += q[j] * bp[j];
  }
  #pragma unroll
  for (int off = 1; off < 8; off <<= 1) {
    qw0 += __shfl_xor(qw0, off, 64);
    qw1 += __shfl_xor(qw1, off, 64);
    qw2 += __shfl_xor(qw2, off, 64);
    qb  += __shfl_xor(qb, off, 64);
  }

  const float4 qp = posf4s[qs];
  const int* ip = idx + (size_t)qs * KNB;
  int nb[KNB];
  #pragma unroll
  for (int k = 0; k < KNB; ++k) nb[k] = base + ip[k];   // sorted row

  float sc[KNB];
  #pragma unroll
  for (int k = 0; k < KNB; ++k) {
    const size_t jg = (size_t)nb[k];
    const float* kr = Kb + jg * D_MODEL + lane * 8;
    float kk[8];
    *(float4*)&kk[0] = *(const float4*)(kr);
    *(float4*)&kk[4] = *(const float4*)(kr + 4);
    float pdot = 0.f;
    #pragma unroll
    for (int j2 = 0; j2 < 8; ++j2) pdot += q[j2] * kk[j2];
    #pragma unroll
    for (int off = 1; off < 8; off <<= 1) pdot += __shfl_xor(pdot, off, 64);
    const float4 np = posf4s[jg];
    sc[k] = (pdot + qw0 * (qp.x - np.x) + qw1 * (qp.y - np.y) +
             qw2 * (qp.z - np.z) + qb) * inv_t;
  }

  float m = sc[0];
  #pragma unroll
  for (int k = 1; k < KNB; ++k) m = fmaxf(m, sc[k]);
  float ssum = 0.f;
  #pragma unroll
  for (int k = 0; k < KNB; ++k) { sc[k] = expf(sc[k] - m); ssum += sc[k]; }
  const float inv_s = 1.f / ssum;

  float acc[8];
  #pragma unroll
  for (int j = 0; j < 8; ++j) acc[j] = 0.f;
  #pragma unroll
  for (int k = 0; k < KNB; ++k) {
    const float* vr = Vb + (size_t)nb[k] * D_MODEL + lane * 8;
    float vv[8];
    *(float4*)&vv[0] = *(const float4*)(vr);
    *(float4*)&vv[4] = *(const float4*)(vr + 4);
    const float wk = sc[k];
    #pragma unroll
    for (int j = 0; j < 8; ++j) acc[j] += wk * vv[j];
  }

  ushort4 hi0, hi1, lo0, lo1;
  unsigned short* oh = Aout + (size_t)qs * 1024 + lane * 8;
  unsigned short* ol = oh + 512;
  float a0 = acc[0] * inv_s, a1 = acc[1] * inv_s, a2 = acc[2] * inv_s, a3 = acc[3] * inv_s;
  float a4 = acc[4] * inv_s, a5 = acc[5] * inv_s, a6 = acc[6] * inv_s, a7 = acc[7] * inv_s;
  hi0.x = f2bf(a0); lo0.x = f2bf(a0 - bf2f(hi0.x));
  hi0.y = f2bf(a1); lo0.y = f2bf(a1 - bf2f(hi0.y));
  hi0.z = f2bf(a2); lo0.z = f2bf(a2 - bf2f(hi0.z));
  hi0.w = f2bf(a3); lo0.w = f2bf(a3 - bf2f(hi0.w));
  hi1.x = f2bf(a4); lo1.x = f2bf(a4 - bf2f(hi1.x));
  hi1.y = f2bf(a5); lo1.y = f2bf(a5 - bf2f(hi1.y));
  hi1.z = f2bf(a6); lo1.z = f2bf(a6 - bf2f(hi1.z));
  hi1.w = f2bf(a7); lo1.w = f2bf(a7 - bf2f(hi1.w));
  *(ushort4*)(oh) = hi0;
  *(ushort4*)(oh + 4) = hi1;
  *(ushort4*)(ol) = lo0;
  *(ushort4*)(ol + 4) = lo1;
}

// ---------------------------------------------------------------------------
// Kernel 5: LN over sorted proj rows, un-permuting on the final write.
// ---------------------------------------------------------------------------
__global__ __launch_bounds__(256) void ln_kernel(const float* __restrict__ proj,
                                                 const float* __restrict__ feat,
                                                 const int* __restrict__ perm,
                                                 const float* __restrict__ bo,
                                                 const float* __restrict__ gamma,
                                                 const float* __restrict__ beta,
                                                 float* __restrict__ out) {
  const int row = blockIdx.x * 4 + (threadIdx.x >> 6);
  const int lane = threadIdx.x & 63;
  const int orig = (row & ~4095) + perm[row];
  const float* pr = proj + (size_t)row * D_MODEL;
  const float* fr = feat + (size_t)orig * D_MODEL;

  float x[8];
  #pragma unroll
  for (int u = 0; u < 2; ++u) {
    const int c = u * 256 + lane * 4;
    const float4 p = *(const float4*)(pr + c);
    const float4 f = *(const float4*)(fr + c);
    const float4 bb = *(const float4*)(bo + c);
    x[u * 4 + 0] = p.x + bb.x + f.x;
    x[u * 4 + 1] = p.y + bb.y + f.y;
    x[u * 4 + 2] = p.z + bb.z + f.z;
    x[u * 4 + 3] = p.w + bb.w + f.w;
  }
  float sum = 0.f, sumsq = 0.f;
  #pragma unroll
  for (int i = 0; i < 8; ++i) { sum += x[i]; sumsq += x[i] * x[i]; }
  sum = wave_reduce_sum(sum);
  sumsq = wave_reduce_sum(sumsq);
  const float mu = sum * (1.f / D_MODEL);
  const float var = sumsq * (1.f / D_MODEL) - mu * mu;
  const float rstd = rsqrtf(var + LN_EPS);

  #pragma unroll
  for (int u = 0; u < 2; ++u) {
    const int c = u * 256 + lane * 4;
    const float4 g = *(const float4*)(gamma + c);
    const float4 bt = *(const float4*)(beta + c);
    float4 o;
    o.x = (x[u * 4 + 0] - mu) * rstd * g.x + bt.x;
    o.y = (x[u * 4 + 1] - mu) * rstd * g.y + bt.y;
    o.z = (x[u * 4 + 2] - mu) * rstd * g.z + bt.z;
    o.w = (x[u * 4 + 3] - mu) * rstd * g.w + bt.w;
    *(float4*)(out + (size_t)orig * D_MODEL + c) = o;
  }
}

// ---------------------------------------------------------------------------
extern "C" void kernel_launch(void* const* d_in, const int* in_sizes, int n_in,
                              void* d_out, int out_size, void* d_ws, size_t ws_size,
                              hipStream_t stream) {
  const float* positions = (const float*)d_in[0];
  const float* features  = (const float*)d_in[1];
  const float* Wq   = (const float*)d_in[3];
  const float* Wk   = (const float*)d_in[4];
  const float* Wv   = (const float*)d_in[5];
  const float* Wo   = (const float*)d_in[6];
  const float* bo   = (const float*)d_in[7];
  const float* Wpos = (const float*)d_in[8];
  const float* bpos = (const float*)d_in[9];
  const float* temp = (const float*)d_in[10];
  const float* gamma = (const float*)d_in[11];
  const float* beta  = (const float*)d_in[12];

  const int B = 2, N = 4096;
  const int BN = B * N;

  char* w = (char*)d_ws;
  float4* posf4  = (float4*)w;             w += (size_t)BN * sizeof(float4);
  float4* posf4s = (float4*)w;             w += (size_t)BN * sizeof(float4);
  int*    idxb   = (int*)w;                w += (size_t)BN * KNB * sizeof(int);
  int*    permb  = (int*)w;                w += (size_t)BN * sizeof(int);
  int*    histb  = (int*)w;                w += (size_t)B * NBUCK * sizeof(int);
  int*    offb   = (int*)w;                w += (size_t)B * NBUCK * sizeof(int);
  int*    buckb  = (int*)w;                w += (size_t)BN * sizeof(int);
  unsigned short* Abuf = (unsigned short*)w; w += (size_t)BN * 1024 * 2;
  unsigned short* BhQKV = (unsigned short*)w; w += (size_t)1536 * 512 * 2;
  unsigned short* BlQKV = (unsigned short*)w; w += (size_t)1536 * 512 * 2;
  unsigned short* BhO = (unsigned short*)w;   w += (size_t)512 * 512 * 2;
  unsigned short* BlO = (unsigned short*)w;   w += (size_t)512 * 512 * 2;
  float* Qb   = (float*)w;                 w += (size_t)BN * D_MODEL * sizeof(float);
  float* Kbuf = (float*)w;                 w += (size_t)BN * D_MODEL * sizeof(float);
  float* Vbuf = (float*)d_out;             // dead before LN overwrites d_out
  float* projb = Kbuf;                     // K dead after attention

  zero_hist_kernel<<<(B * NBUCK + 255) / 256, 256, 0, stream>>>(histb, B * NBUCK);
  bucket_kernel<<<(BN + 255) / 256, 256, 0, stream>>>(positions, posf4, histb,
                                                      buckb, BN);
  scan_kernel<<<B, 1024, 0, stream>>>(histb, offb);
  scatter_kernel<<<(BN + 255) / 256, 256, 0, stream>>>(posf4, buckb, offb,
                                                       permb, posf4s, BN);
  knn_kernel<<<BN, 64, 0, stream>>>(posf4s, idxb, N);

  conv_feat_kernel<<<(BN * D_MODEL / 4 + 255) / 256, 256, 0, stream>>>(
      features, permb, Abuf, BN * D_MODEL / 4);
  conv_w_kernel<<<4096, 256, 0, stream>>>(Wq, Wk, Wv, Wo, BhQKV, BlQKV, BhO, BlO);

  gemm_split_kernel<<<768, 256, 0, stream>>>(
      Abuf, BhQKV, BlQKV, Qb, Kbuf, Vbuf, 12);

  attn_kernel<<<BN / 4, 256, 0, stream>>>(Qb, Kbuf, Vbuf, idxb,
                                          posf4s, Wpos, bpos, temp, Abuf,
                                          BN / 4);

  gemm_split_kernel<<<256, 256, 0, stream>>>(
      Abuf, BhO, BlO, projb, projb, projb, 4);

  ln_kernel<<<BN / 4, 256, 0, stream>>>(projb, features, permb, bo, gamma, beta,
                                        (float*)d_out);
}

// Round 16
// 262.514 us; speedup vs baseline: 1.1083x; 1.0266x over previous
//
#include <hip/hip_runtime.h>
#include <cstdint>

#define D_MODEL 512
#define NUM_HEADS 8
#define D_HEAD 64
#define KNB 16
#define NBUCK 2048
#define KCAP 256
#define LN_EPS 1e-5f
#define FINF 3.4e38f

typedef __bf16 bf16x8v __attribute__((ext_vector_type(8)));
typedef float f32x4v __attribute__((ext_vector_type(4)));
typedef int i32x4 __attribute__((ext_vector_type(4)));
typedef const __attribute__((address_space(1))) unsigned int* gptr_t;
typedef __attribute__((address_space(3))) unsigned int* lptr_t;

__device__ __forceinline__ float wave_reduce_sum(float v) {
  #pragma unroll
  for (int off = 32; off > 0; off >>= 1) v += __shfl_xor(v, off, 64);
  return v;
}

// bf16 helpers (bit-level, round-to-nearest-even)
__device__ __forceinline__ unsigned short f2bf(float x) {
  unsigned int u = __float_as_uint(x);
  u = (u + 0x7fffu + ((u >> 16) & 1u)) >> 16;
  return (unsigned short)u;
}
__device__ __forceinline__ float bf2f(unsigned short h) {
  return __uint_as_float(((unsigned int)h) << 16);
}

// Morton helpers: bucketing quality only affects SPEED.
__device__ __forceinline__ unsigned spread3(unsigned x) {
  x &= 0x3FFu;
  x = (x | (x << 16)) & 0x030000FFu;
  x = (x | (x << 8))  & 0x0300F00Fu;
  x = (x | (x << 4))  & 0x030C30C3u;
  x = (x | (x << 2))  & 0x09249249u;
  return x;
}
__device__ __forceinline__ unsigned quant10(float v) {
  int q = (int)((v + 6.f) * (1023.f / 12.f));
  q = q < 0 ? 0 : (q > 1023 ? 1023 : q);
  return (unsigned)q;
}

// 64-lane bitonic sort ascending by (d, j) lexicographic (pairs distinct).
__device__ __forceinline__ void bitonic64(float& d, int& j, int lane) {
  #pragma unroll
  for (int k = 2; k <= 64; k <<= 1) {
    #pragma unroll
    for (int s = k >> 1; s > 0; s >>= 1) {
      const float od = __shfl_xor(d, s, 64);
      const int   oj = __shfl_xor(j, s, 64);
      const bool up = ((lane & k) == 0);
      const bool lower = ((lane & s) == 0);
      const bool oless = (od < d) || (od == d && oj < j);
      if ((lower == up) ? oless : !oless) { d = od; j = oj; }
    }
  }
}

// ---------------------------------------------------------------------------
// Kernel 0a: zero bucket histogram
// ---------------------------------------------------------------------------
__global__ void zero_hist_kernel(int* __restrict__ hist, int n) {
  const int t = blockIdx.x * blockDim.x + threadIdx.x;
  if (t < n) hist[t] = 0;
}

// ---------------------------------------------------------------------------
// Kernel 0b: pad pos -> float4, Morton bucket (top 11 bits), histogram.
// ---------------------------------------------------------------------------
__global__ void bucket_kernel(const float* __restrict__ pos,
                              float4* __restrict__ posf4,
                              int* __restrict__ hist,
                              int* __restrict__ bucketid, int total) {
  const int t = blockIdx.x * blockDim.x + threadIdx.x;
  if (t >= total) return;
  const float4 p = make_float4(pos[t * 3], pos[t * 3 + 1], pos[t * 3 + 2], 0.f);
  posf4[t] = p;
  const unsigned code = (spread3(quant10(p.z)) << 2) |
                        (spread3(quant10(p.y)) << 1) | spread3(quant10(p.x));
  const int bk = code >> 19;
  const int b = t >> 12;
  bucketid[t] = bk;
  atomicAdd(&hist[b * NBUCK + bk], 1);
}

// ---------------------------------------------------------------------------
// Kernel 0c: exclusive scan of 2048 buckets per batch (one block per batch).
// ---------------------------------------------------------------------------
__global__ __launch_bounds__(1024) void scan_kernel(const int* __restrict__ hist,
                                                    int* __restrict__ off) {
  __shared__ int lsum[16];
  const int b = blockIdx.x;
  const int tid = threadIdx.x;
  const int lane = tid & 63, wv = tid >> 6;
  const int h0 = hist[b * NBUCK + 2 * tid];
  const int h1 = hist[b * NBUCK + 2 * tid + 1];
  int v = h0 + h1;
  #pragma unroll
  for (int d = 1; d < 64; d <<= 1) {
    const int u = __shfl_up(v, d, 64);
    if (lane >= d) v += u;
  }
  if (lane == 63) lsum[wv] = v;
  __syncthreads();
  if (wv == 0) {
    int s = (lane < 16) ? lsum[lane] : 0;
    #pragma unroll
    for (int d = 1; d < 16; d <<= 1) {
      const int u = __shfl_up(s, d, 64);
      if (lane >= d) s += u;
    }
    if (lane < 16) lsum[lane] = s;
  }
  __syncthreads();
  const int base = (wv > 0) ? lsum[wv - 1] : 0;
  const int excl = v + base - (h0 + h1);
  off[b * NBUCK + 2 * tid] = excl;
  off[b * NBUCK + 2 * tid + 1] = excl + h0;
}

// ---------------------------------------------------------------------------
// Kernel 0d: scatter into bucket order.
// ---------------------------------------------------------------------------
__global__ void scatter_kernel(const float4* __restrict__ posf4,
                               const int* __restrict__ bucketid,
                               int* __restrict__ off,
                               int* __restrict__ perm,
                               float4* __restrict__ posf4s, int total) {
  const int t = blockIdx.x * blockDim.x + threadIdx.x;
  if (t >= total) return;
  const int b = t >> 12;
  const int i = t & 4095;
  const int slot = atomicAdd(&off[b * NBUCK + bucketid[t]], 1);
  perm[b * 4096 + slot] = i;
  posf4s[b * 4096 + slot] = posf4[t];
}

// ---------------------------------------------------------------------------
// Kernel 1: kNN — register-resident single scan + bitonic selection
// (unchanged from Round 12: measured fast, out of top-5).
// ---------------------------------------------------------------------------
__global__ __launch_bounds__(64) void knn_kernel(const float4* __restrict__ posf4s,
                                                 int* __restrict__ idx_out,
                                                 int N) {
  __shared__ float ldsD[KCAP];
  __shared__ int   ldsJ[KCAP];
  const int qs = blockIdx.x;           // global sorted id
  const int base = qs & ~4095;
  const int n = qs - base;             // batch-local sorted pos
  const int lane = threadIdx.x;
  const float4* pb = posf4s + base;
  const float4 qp = pb[n];

  float darr[64];
  float lmin = FINF;
  #pragma unroll
  for (int it = 0; it < 64; ++it) {
    const int j = (it << 6) + lane;
    const float4 p = pb[j];
    const float dx = qp.x - p.x, dy = qp.y - p.y, dz = qp.z - p.z;
    float d = dx * dx + dy * dy + dz * dz;
    if (j == n) d = FINF;
    darr[it] = d;
    lmin = fminf(lmin, d);
  }

  float tau;
  {
    float dm = lmin;
    int jm = lane;
    bitonic64(dm, jm, lane);
    tau = __shfl(dm, 15, 64);
  }

  int count = 0;
  #pragma unroll
  for (int it = 0; it < 64; ++it) {
    const float d = darr[it];
    const bool pred = (d <= tau);
    const unsigned long long mask = __ballot(pred);
    if (pred) {
      const int slot = count + __popcll(mask & ((1ull << lane) - 1ull));
      if (slot < KCAP) { ldsD[slot] = d; ldsJ[slot] = (it << 6) + lane; }
    }
    count += (int)__popcll(mask);
  }

  if (count <= KCAP) {
    float d = (lane < count) ? ldsD[lane] : FINF;
    int   jj = (lane < count) ? ldsJ[lane] : 0x40000000 + lane;
    bitonic64(d, jj, lane);
    for (int start = 64; start < count; start += 48) {
      if (lane >= 16) {
        const int src = start + lane - 16;
        d  = (src < count) ? ldsD[src] : FINF;
        jj = (src < count) ? ldsJ[src] : 0x40000000 + lane;
      }
      bitonic64(d, jj, lane);
    }
    if (lane < KNB) idx_out[qs * KNB + lane] = jj;
  } else {
    float dist[KNB];
    int nidx[KNB];
    #pragma unroll
    for (int t = 0; t < KNB; ++t) { dist[t] = FINF; nidx[t] = -1; }
    #pragma unroll
    for (int it = 0; it < 64; ++it) {
      const float d = darr[it];
      unsigned long long mask = __ballot(d <= tau);
      while (mask) {
        const int src = __builtin_ctzll(mask);
        mask &= (mask - 1);
        const float dd = __shfl(d, src, 64);
        const int jj = (it << 6) + src;
        if (dd < dist[KNB - 1]) {
          float dc = dd;
          int ic = jj;
          #pragma unroll
          for (int t = 0; t < KNB; ++t) {
            const bool sw = dc < dist[t];
            const float od = dist[t];
            const int oi = nidx[t];
            dist[t] = sw ? dc : od;
            nidx[t] = sw ? ic : oi;
            dc = sw ? od : dc;
            ic = sw ? oi : ic;
          }
        }
      }
    }
    #pragma unroll
    for (int t = 0; t < KNB; ++t) {
      const int v = nidx[t] < 0 ? 0 : nidx[t];
      if (lane == t) idx_out[qs * KNB + t] = v;
    }
  }
}

// ---------------------------------------------------------------------------
// Kernel 2a: features -> A' bf16 Mx1024 [hi|lo], rows gathered into sorted
// order.
// ---------------------------------------------------------------------------
__global__ __launch_bounds__(256) void conv_feat_kernel(const float* __restrict__ src,
                                                        const int* __restrict__ perm,
                                                        unsigned short* __restrict__ dst,
                                                        int total4) {
  const int t = blockIdx.x * blockDim.x + threadIdx.x;
  if (t >= total4) return;
  const int f = t * 4;
  const int row = f >> 9;
  const int col = f & 511;
  const int orig = (row & ~4095) + perm[row];
  const float4 v = *(const float4*)(src + (size_t)orig * 512 + col);
  ushort4 h, l;
  h.x = f2bf(v.x); l.x = f2bf(v.x - bf2f(h.x));
  h.y = f2bf(v.y); l.y = f2bf(v.y - bf2f(h.y));
  h.z = f2bf(v.z); l.z = f2bf(v.z - bf2f(h.z));
  h.w = f2bf(v.w); l.w = f2bf(v.w - bf2f(h.w));
  *(ushort4*)(dst + (size_t)row * 1024 + col) = h;
  *(ushort4*)(dst + (size_t)row * 1024 + 512 + col) = l;
}

// ---------------------------------------------------------------------------
// Kernel 2b: weights (512x512 fp32, W[k][n]) -> transposed split bf16
// ---------------------------------------------------------------------------
__global__ __launch_bounds__(256) void conv_w_kernel(const float* __restrict__ Wq,
                                                     const float* __restrict__ Wk,
                                                     const float* __restrict__ Wv,
                                                     const float* __restrict__ Wo,
                                                     unsigned short* __restrict__ BhQKV,
                                                     unsigned short* __restrict__ BlQKV,
                                                     unsigned short* __restrict__ BhO,
                                                     unsigned short* __restrict__ BlO) {
  const int wsel = blockIdx.x >> 10;
  const int i = ((blockIdx.x & 1023) << 8) + threadIdx.x;
  const int n = i >> 9;
  const int k = i & 511;
  const float* src = wsel == 0 ? Wq : wsel == 1 ? Wk : wsel == 2 ? Wv : Wo;
  unsigned short* dh = wsel < 3 ? BhQKV + (size_t)(wsel * 512 + n) * 512
                                : BhO + (size_t)n * 512;
  unsigned short* dl = wsel < 3 ? BlQKV + (size_t)(wsel * 512 + n) * 512
                                : BlO + (size_t)n * 512;
  const float w = src[(size_t)k * 512 + n];
  const unsigned short h = f2bf(w);
  dh[k] = h;
  dl[k] = f2bf(w - bf2f(h));
}

// ---------------------------------------------------------------------------
// Kernel 3: split-bf16 MFMA GEMM (unchanged from Round 15: XCD-aware grid,
// BK=64, XOR swizzle).
// ---------------------------------------------------------------------------
__global__ __launch_bounds__(256) void gemm_split_kernel(
    const unsigned short* __restrict__ A,    // M x 1024  [hi|lo]
    const unsigned short* __restrict__ Bh,   // Ncols x 512
    const unsigned short* __restrict__ Bl,   // Ncols x 512
    float* __restrict__ C0, float* __restrict__ C1, float* __restrict__ C2,
    int nbn) {
  __shared__ unsigned short AsH[8192];   // 128 rows x 64 halves (16 KB)
  __shared__ unsigned short AsL[8192];
  __shared__ unsigned short Bs[8192];

  const int tid = threadIdx.x;
  const int wid = tid >> 6;
  const int lane = tid & 63;
  const int lm = lane & 15;
  const int kq = lane >> 4;
  const int wr = wid >> 1;
  const int wc = wid & 1;
  const int bid = blockIdx.x;
  const int xcd = bid & 7;
  const int i = bid >> 3;
  const int bm = xcd * 8 + i / nbn;
  const int bn = i % nbn;
  const int rowA0 = bm * 128;
  const int rowB0 = bn * 128;

  f32x4v acc[4][4];
  #pragma unroll
  for (int mi = 0; mi < 4; ++mi)
    #pragma unroll
    for (int ni = 0; ni < 4; ++ni) {
      f32x4v z = {0.f, 0.f, 0.f, 0.f};
      acc[mi][ni] = z;
    }

  auto stage64 = [&](unsigned short* dst, const unsigned short* gsrc,
                     int gstride, int grow0, int gk0) {
    #pragma unroll
    for (int i2 = 0; i2 < 4; ++i2) {
      const int c = wid * 256 + i2 * 64 + lane;   // chunk 0..1023
      const int row = c >> 3;
      const int gq = (c & 7) ^ (row & 7);
      const unsigned short* ga =
          gsrc + (size_t)(grow0 + row) * gstride + gk0 + gq * 8;
      __builtin_amdgcn_global_load_lds((gptr_t)ga,
          (lptr_t)(dst + (size_t)(wid * 256 + i2 * 64) * 8), 16, 0, 0);
    }
  };
  auto rd64 = [&](const unsigned short* src, int row, int g) -> i32x4 {
    const int sl = row * 8 + (g ^ (row & 7));
    return *(const i32x4*)(src + (size_t)sl * 8);
  };

  // ---- loop 1: (A_hi + A_lo) x B_hi, 64 MFMA per barrier ----
  for (int k0 = 0; k0 < 512; k0 += 64) {
    stage64(AsH, A, 1024, rowA0, k0);
    stage64(AsL, A, 1024, rowA0, 512 + k0);
    stage64(Bs, Bh, 512, rowB0, k0);
    __syncthreads();
    #pragma unroll
    for (int kh = 0; kh < 2; ++kh) {
      const int g = kh * 4 + kq;
      i32x4 ah[4], al[4], bb[4];
      #pragma unroll
      for (int mi = 0; mi < 4; ++mi) {
        ah[mi] = rd64(AsH, wr * 64 + mi * 16 + lm, g);
        al[mi] = rd64(AsL, wr * 64 + mi * 16 + lm, g);
      }
      #pragma unroll
      for (int ni = 0; ni < 4; ++ni)
        bb[ni] = rd64(Bs, wc * 64 + ni * 16 + lm, g);
      #pragma unroll
      for (int mi = 0; mi < 4; ++mi)
        #pragma unroll
        for (int ni = 0; ni < 4; ++ni) {
          acc[mi][ni] = __builtin_amdgcn_mfma_f32_16x16x32_bf16(
              __builtin_bit_cast(bf16x8v, ah[mi]),
              __builtin_bit_cast(bf16x8v, bb[ni]), acc[mi][ni], 0, 0, 0);
          acc[mi][ni] = __builtin_amdgcn_mfma_f32_16x16x32_bf16(
              __builtin_bit_cast(bf16x8v, al[mi]),
              __builtin_bit_cast(bf16x8v, bb[ni]), acc[mi][ni], 0, 0, 0);
        }
    }
    __syncthreads();
  }

  // ---- loop 2: A_hi x B_lo, 32 MFMA per barrier ----
  for (int k0 = 0; k0 < 512; k0 += 64) {
    stage64(AsH, A, 1024, rowA0, k0);
    stage64(Bs, Bl, 512, rowB0, k0);
    __syncthreads();
    #pragma unroll
    for (int kh = 0; kh < 2; ++kh) {
      const int g = kh * 4 + kq;
      i32x4 ah[4], bb[4];
      #pragma unroll
      for (int mi = 0; mi < 4; ++mi)
        ah[mi] = rd64(AsH, wr * 64 + mi * 16 + lm, g);
      #pragma unroll
      for (int ni = 0; ni < 4; ++ni)
        bb[ni] = rd64(Bs, wc * 64 + ni * 16 + lm, g);
      #pragma unroll
      for (int mi = 0; mi < 4; ++mi)
        #pragma unroll
        for (int ni = 0; ni < 4; ++ni)
          acc[mi][ni] = __builtin_amdgcn_mfma_f32_16x16x32_bf16(
              __builtin_bit_cast(bf16x8v, ah[mi]),
              __builtin_bit_cast(bf16x8v, bb[ni]), acc[mi][ni], 0, 0, 0);
    }
    __syncthreads();
  }

  const int sel = bn >> 2;
  float* __restrict__ Cb = sel == 0 ? C0 : sel == 1 ? C1 : C2;
  const int r0 = bm * 128 + wr * 64;
  const int c0 = ((bn & 3) << 7) + wc * 64;
  // C/D layout: col = lane&15, row = (lane>>4)*4 + reg   [m89/m91]
  #pragma unroll
  for (int mi = 0; mi < 4; ++mi)
    #pragma unroll
    for (int ni = 0; ni < 4; ++ni) {
      float* Cp = Cb + (size_t)(r0 + mi * 16 + kq * 4) * 512 + c0 + ni * 16 + lm;
      #pragma unroll
      for (int r = 0; r < 4; ++r) Cp[(size_t)r * 512] = acc[mi][ni][r];
    }
}

// ---------------------------------------------------------------------------
// Kernel 4: local attention — Round 16: REGISTER-BATCHED gathers.
// r15 counters (occ 26%, VALU 24%, HBM 14%, VGPR 76): per-wave gather loads
// ran ~serialized (~200cyc each, ~70/wave ≈ block time) because the compiler
// kept too few loads in flight at 76 VGPRs. Fix (same mechanism that made
// r12's knn fast): explicit register batches — pe pre-pass loads all 16
// neighbor positions at once; score and V loops process 8 neighbors per
// batch with all 16 float4 loads issued before any use. VGPR rises to
// ~130-150 (3 waves/SIMD) but memory parallelism rises ~5-8x.
// Arithmetic identical to r15 (same ops, same order per neighbor).
// ---------------------------------------------------------------------------
__global__ __launch_bounds__(256) void attn_kernel(const float* __restrict__ Q,
                                                   const float* __restrict__ Kb,
                                                   const float* __restrict__ Vb,
                                                   const int* __restrict__ idx,
                                                   const float4* __restrict__ posf4s,
                                                   const float* __restrict__ Wpos,
                                                   const float* __restrict__ bpos,
                                                   const float* __restrict__ temperature,
                                                   unsigned short* __restrict__ Aout,
                                                   int nblocks) {
  int bid = blockIdx.x;
  bid = (bid & 7) * (nblocks >> 3) + (bid >> 3);        // XCD-contiguous
  const int qs = bid * 4 + (threadIdx.x >> 6);
  const int lane = threadIdx.x & 63;
  const int s = lane & 7;
  const int base = qs & ~4095;

  const float inv_t = 1.0f / temperature[0];

  float q[8];
  *(float4*)&q[0] = *(const float4*)(Q + (size_t)qs * D_MODEL + lane * 8);
  *(float4*)&q[4] = *(const float4*)(Q + (size_t)qs * D_MODEL + lane * 8 + 4);

  float wp[3][8], bp[8];
  #pragma unroll
  for (int c = 0; c < 3; ++c) {
    *(float4*)&wp[c][0] = *(const float4*)(Wpos + c * 128 + s * 8);
    *(float4*)&wp[c][4] = *(const float4*)(Wpos + c * 128 + s * 8 + 4);
  }
  *(float4*)&bp[0] = *(const float4*)(bpos + s * 8);
  *(float4*)&bp[4] = *(const float4*)(bpos + s * 8 + 4);
  float qw0 = 0.f, qw1 = 0.f, qw2 = 0.f, qb = 0.f;
  #pragma unroll
  for (int j = 0; j < 8; ++j) {
    qw0 += q[j] * wp[0][j];
    qw1 += q[j] * wp[1][j];
    qw2 += q[j] * wp[2][j];
    qb  += q[j] * bp[j];
  }
  #pragma unroll
  for (int off = 1; off < 8; off <<= 1) {
    qw0 += __shfl_xor(qw0, off, 64);
    qw1 += __shfl_xor(qw1, off, 64);
    qw2 += __shfl_xor(qw2, off, 64);
    qb  += __shfl_xor(qb, off, 64);
  }

  const float4 qp = posf4s[qs];
  const int* ip = idx + (size_t)qs * KNB;
  int nb[KNB];
  #pragma unroll
  for (int k = 0; k < KNB; ++k) nb[k] = base + ip[k];   // sorted row

  // ---- pe pre-pass: all 16 neighbor positions in flight at once ----
  float pe[KNB];
  {
    float4 np[KNB];
    #pragma unroll
    for (int k = 0; k < KNB; ++k) np[k] = posf4s[nb[k]];
    #pragma unroll
    for (int k = 0; k < KNB; ++k)
      pe[k] = qw0 * (qp.x - np[k].x) + qw1 * (qp.y - np[k].y) +
              qw2 * (qp.z - np[k].z) + qb;
  }

  // ---- scores: 2 batches of 8 K-rows, 16 float4 loads in flight ----
  float sc[KNB];
  #pragma unroll
  for (int kb = 0; kb < KNB; kb += 8) {
    float kk[8][8];
    #pragma unroll
    for (int k = 0; k < 8; ++k) {
      const float* kr = Kb + (size_t)nb[kb + k] * D_MODEL + lane * 8;
      *(float4*)&kk[k][0] = *(const float4*)(kr);
      *(float4*)&kk[k][4] = *(const float4*)(kr + 4);
    }
    #pragma unroll
    for (int k = 0; k < 8; ++k) {
      float pdot = 0.f;
      #pragma unroll
      for (int j2 = 0; j2 < 8; ++j2) pdot += q[j2] * kk[k][j2];
      #pragma unroll
      for (int off = 1; off < 8; off <<= 1) pdot += __shfl_xor(pdot, off, 64);
      sc[kb + k] = (pdot + pe[kb + k]) * inv_t;
    }
  }

  float m = sc[0];
  #pragma unroll
  for (int k = 1; k < KNB; ++k) m = fmaxf(m, sc[k]);
  float ssum = 0.f;
  #pragma unroll
  for (int k = 0; k < KNB; ++k) { sc[k] = expf(sc[k] - m); ssum += sc[k]; }
  const float inv_s = 1.f / ssum;

  // ---- weighted V: 2 batches of 8 rows ----
  float acc[8];
  #pragma unroll
  for (int j = 0; j < 8; ++j) acc[j] = 0.f;
  #pragma unroll
  for (int kb = 0; kb < KNB; kb += 8) {
    float vv[8][8];
    #pragma unroll
    for (int k = 0; k < 8; ++k) {
      const float* vr = Vb + (size_t)nb[kb + k] * D_MODEL + lane * 8;
      *(float4*)&vv[k][0] = *(const float4*)(vr);
      *(float4*)&vv[k][4] = *(const float4*)(vr + 4);
    }
    #pragma unroll
    for (int k = 0; k < 8; ++k) {
      const float wk = sc[kb + k];
      #pragma unroll
      for (int j = 0; j < 8; ++j) acc[j] += wk * vv[k][j];
    }
  }

  ushort4 hi0, hi1, lo0, lo1;
  unsigned short* oh = Aout + (size_t)qs * 1024 + lane * 8;
  unsigned short* ol = oh + 512;
  float a0 = acc[0] * inv_s, a1 = acc[1] * inv_s, a2 = acc[2] * inv_s, a3 = acc[3] * inv_s;
  float a4 = acc[4] * inv_s, a5 = acc[5] * inv_s, a6 = acc[6] * inv_s, a7 = acc[7] * inv_s;
  hi0.x = f2bf(a0); lo0.x = f2bf(a0 - bf2f(hi0.x));
  hi0.y = f2bf(a1); lo0.y = f2bf(a1 - bf2f(hi0.y));
  hi0.z = f2bf(a2); lo0.z = f2bf(a2 - bf2f(hi0.z));
  hi0.w = f2bf(a3); lo0.w = f2bf(a3 - bf2f(hi0.w));
  hi1.x = f2bf(a4); lo1.x = f2bf(a4 - bf2f(hi1.x));
  hi1.y = f2bf(a5); lo1.y = f2bf(a5 - bf2f(hi1.y));
  hi1.z = f2bf(a6); lo1.z = f2bf(a6 - bf2f(hi1.z));
  hi1.w = f2bf(a7); lo1.w = f2bf(a7 - bf2f(hi1.w));
  *(ushort4*)(oh) = hi0;
  *(ushort4*)(oh + 4) = hi1;
  *(ushort4*)(ol) = lo0;
  *(ushort4*)(ol + 4) = lo1;
}

// ---------------------------------------------------------------------------
// Kernel 5: LN over sorted proj rows, un-permuting on the final write.
// ---------------------------------------------------------------------------
__global__ __launch_bounds__(256) void ln_kernel(const float* __restrict__ proj,
                                                 const float* __restrict__ feat,
                                                 const int* __restrict__ perm,
                                                 const float* __restrict__ bo,
                                                 const float* __restrict__ gamma,
                                                 const float* __restrict__ beta,
                                                 float* __restrict__ out) {
  const int row = blockIdx.x * 4 + (threadIdx.x >> 6);
  const int lane = threadIdx.x & 63;
  const int orig = (row & ~4095) + perm[row];
  const float* pr = proj + (size_t)row * D_MODEL;
  const float* fr = feat + (size_t)orig * D_MODEL;

  float x[8];
  #pragma unroll
  for (int u = 0; u < 2; ++u) {
    const int c = u * 256 + lane * 4;
    const float4 p = *(const float4*)(pr + c);
    const float4 f = *(const float4*)(fr + c);
    const float4 bb = *(const float4*)(bo + c);
    x[u * 4 + 0] = p.x + bb.x + f.x;
    x[u * 4 + 1] = p.y + bb.y + f.y;
    x[u * 4 + 2] = p.z + bb.z + f.z;
    x[u * 4 + 3] = p.w + bb.w + f.w;
  }
  float sum = 0.f, sumsq = 0.f;
  #pragma unroll
  for (int i = 0; i < 8; ++i) { sum += x[i]; sumsq += x[i] * x[i]; }
  sum = wave_reduce_sum(sum);
  sumsq = wave_reduce_sum(sumsq);
  const float mu = sum * (1.f / D_MODEL);
  const float var = sumsq * (1.f / D_MODEL) - mu * mu;
  const float rstd = rsqrtf(var + LN_EPS);

  #pragma unroll
  for (int u = 0; u < 2; ++u) {
    const int c = u * 256 + lane * 4;
    const float4 g = *(const float4*)(gamma + c);
    const float4 bt = *(const float4*)(beta + c);
    float4 o;
    o.x = (x[u * 4 + 0] - mu) * rstd * g.x + bt.x;
    o.y = (x[u * 4 + 1] - mu) * rstd * g.y + bt.y;
    o.z = (x[u * 4 + 2] - mu) * rstd * g.z + bt.z;
    o.w = (x[u * 4 + 3] - mu) * rstd * g.w + bt.w;
    *(float4*)(out + (size_t)orig * D_MODEL + c) = o;
  }
}

// ---------------------------------------------------------------------------
extern "C" void kernel_launch(void* const* d_in, const int* in_sizes, int n_in,
                              void* d_out, int out_size, void* d_ws, size_t ws_size,
                              hipStream_t stream) {
  const float* positions = (const float*)d_in[0];
  const float* features  = (const float*)d_in[1];
  const float* Wq   = (const float*)d_in[3];
  const float* Wk   = (const float*)d_in[4];
  const float* Wv   = (const float*)d_in[5];
  const float* Wo   = (const float*)d_in[6];
  const float* bo   = (const float*)d_in[7];
  const float* Wpos = (const float*)d_in[8];
  const float* bpos = (const float*)d_in[9];
  const float* temp = (const float*)d_in[10];
  const float* gamma = (const float*)d_in[11];
  const float* beta  = (const float*)d_in[12];

  const int B = 2, N = 4096;
  const int BN = B * N;

  char* w = (char*)d_ws;
  float4* posf4  = (float4*)w;             w += (size_t)BN * sizeof(float4);
  float4* posf4s = (float4*)w;             w += (size_t)BN * sizeof(float4);
  int*    idxb   = (int*)w;                w += (size_t)BN * KNB * sizeof(int);
  int*    permb  = (int*)w;                w += (size_t)BN * sizeof(int);
  int*    histb  = (int*)w;                w += (size_t)B * NBUCK * sizeof(int);
  int*    offb   = (int*)w;                w += (size_t)B * NBUCK * sizeof(int);
  int*    buckb  = (int*)w;                w += (size_t)BN * sizeof(int);
  unsigned short* Abuf = (unsigned short*)w; w += (size_t)BN * 1024 * 2;
  unsigned short* BhQKV = (unsigned short*)w; w += (size_t)1536 * 512 * 2;
  unsigned short* BlQKV = (unsigned short*)w; w += (size_t)1536 * 512 * 2;
  unsigned short* BhO = (unsigned short*)w;   w += (size_t)512 * 512 * 2;
  unsigned short* BlO = (unsigned short*)w;   w += (size_t)512 * 512 * 2;
  float* Qb   = (float*)w;                 w += (size_t)BN * D_MODEL * sizeof(float);
  float* Kbuf = (float*)w;                 w += (size_t)BN * D_MODEL * sizeof(float);
  float* Vbuf = (float*)d_out;             // dead before LN overwrites d_out
  float* projb = Kbuf;                     // K dead after attention

  zero_hist_kernel<<<(B * NBUCK + 255) / 256, 256, 0, stream>>>(histb, B * NBUCK);
  bucket_kernel<<<(BN + 255) / 256, 256, 0, stream>>>(positions, posf4, histb,
                                                      buckb, BN);
  scan_kernel<<<B, 1024, 0, stream>>>(histb, offb);
  scatter_kernel<<<(BN + 255) / 256, 256, 0, stream>>>(posf4, buckb, offb,
                                                       permb, posf4s, BN);
  knn_kernel<<<BN, 64, 0, stream>>>(posf4s, idxb, N);

  conv_feat_kernel<<<(BN * D_MODEL / 4 + 255) / 256, 256, 0, stream>>>(
      features, permb, Abuf, BN * D_MODEL / 4);
  conv_w_kernel<<<4096, 256, 0, stream>>>(Wq, Wk, Wv, Wo, BhQKV, BlQKV, BhO, BlO);

  gemm_split_kernel<<<768, 256, 0, stream>>>(
      Abuf, BhQKV, BlQKV, Qb, Kbuf, Vbuf, 12);

  attn_kernel<<<BN / 4, 256, 0, stream>>>(Qb, Kbuf, Vbuf, idxb,
                                          posf4s, Wpos, bpos, temp, Abuf,
                                          BN / 4);

  gemm_split_kernel<<<256, 256, 0, stream>>>(
      Abuf, BhO, BlO, projb, projb, projb, 4);

  ln_kernel<<<BN / 4, 256, 0, stream>>>(projb, features, permb, bo, gamma, beta,
                                        (float*)d_out);
}